// Round 17
// baseline (118.747 us; speedup 1.0000x reference)
//
#include <hip/hip_runtime.h>
#include <math.h>

typedef __attribute__((ext_vector_type(8))) short short8v;   // 8 bf16
typedef __attribute__((ext_vector_type(16))) float f32x16;   // MFMA acc

// ws layout:
//  ushort offsets:
//   basisF (fdft) [cc128][tbl4][kh2][m64][e8]    @ u 0        (524288 u)
//     tbl: 0=cosHi 1=cosLo 2=(-sin)Hi 3=(-sin)Lo ; t = cc*16 + kh*8 + e
//   basisI (idft) [slab4][tbl4][kh2][t1088][e8]  @ u 524288   (278528 u)
//     tbl: 0=cosHi 1=cosLo 2=sinHi 3=sinLo ; m = slab*16 + kh*8 + e
//  float offsets:
//   XP [zz8][b16][p2][h8][m64][e64]              @ f 401408   (8388608 f)
//  ushort offsets:
//   YT [b16][tbl4][ch512][m64]                   @ u 17580032 (2097152 u)
//     tbl: 0=YrHi 1=YrLo 2=YiHi 3=YiLo (Yi sign-folded)
#define BF_U 0
#define BI_U 524288
#define XP_F 401408
#define YT_U 17580032

__device__ inline unsigned short bf16_rne(float x) {
    unsigned int u = __float_as_uint(x);
    u += 0x7FFFu + ((u >> 16) & 1u);
    return (unsigned short)(u >> 16);
}
__device__ inline float bf16_f(unsigned short h) {
    return __uint_as_float(((unsigned int)h) << 16);
}

// async global->LDS, 16 B per lane; l must be wave-uniform, g per-lane.
__device__ inline void gl_lds16(const void* g, void* l) {
    __builtin_amdgcn_global_load_lds(
        (const __attribute__((address_space(1))) unsigned int*)g,
        (__attribute__((address_space(3))) unsigned int*)l, 16, 0, 0);
}

__global__ __launch_bounds__(256) void basis_kernel(float* __restrict__ w) {
    int idx = blockIdx.x * 256 + threadIdx.x;
    const float th = 0.0030679615757712823f; // 2*pi/2048
    unsigned short* bw = (unsigned short*)w;
    if (idx < 131072) {          // fdft tables: t 0..2047, m 0..63
        int t = idx >> 6, m = idx & 63;
        int j = (m * t) & 2047;
        float s, c; sincosf(th * (float)j, &s, &c);
        float ns = -s;
        int cc = t >> 4, kh = (t >> 3) & 1, e = t & 7;
        int base = BF_U + cc * 4096 + kh * 512 + m * 8 + e;
        unsigned short chv = bf16_rne(c), shv = bf16_rne(ns);
        bw[base]        = chv;
        bw[base + 1024] = bf16_rne(c - bf16_f(chv));
        bw[base + 2048] = shv;
        bw[base + 3072] = bf16_rne(ns - bf16_f(shv));
    }
    if (idx < 69632) {           // idft tables
        int m = idx / 1088, t = idx - m * 1088;
        int j = (m * t) & 2047;
        float s, c; sincosf(th * (float)j, &s, &c);
        int slab = m >> 4, kh = (m >> 3) & 1, e = m & 7;
        int base = BI_U + (slab * 8 + kh) * 8704 + t * 8 + e;
        unsigned short chv = bf16_rne(c), shv = bf16_rne(s);
        bw[base]         = chv;
        bw[base + 17408] = bf16_rne(c - bf16_f(chv));
        bw[base + 34816] = shv;
        bw[base + 52224] = bf16_rne(s - bf16_f(shv));
    }
}

// Forward (UNFOLDED) DFT via bf16-split MFMA, global_load_lds staging, DEPTH-3
// triple-buffer pipeline with counted vmcnt (steady state vmcnt(6): chunks
// c+1, c+2 stay in flight across the barrier). Block: 64m x 64ch x t-quarter;
// 4 waves = (m-half x ch-half). Grid (chtile8, b16, zz8) = 1024 blocks.
__global__ __launch_bounds__(256, 4) void fdft_kernel(const float* __restrict__ q,
                                                      const float* __restrict__ k,
                                                      float* __restrict__ ws) {
    const int chtile = blockIdx.x;        // 0..7 (64 ch)
    const int b      = blockIdx.y;
    const int zz     = blockIdx.z;        // tz*4 + part
    const int part   = zz & 3;
    const float* __restrict__ src = (zz >> 2) ? k : q;
    const unsigned short* __restrict__ basisF = (const unsigned short*)ws + BF_U;
    float* __restrict__ xp = ws + XP_F + (size_t)(zz * 16 + b) * 65536;

    // 3 buffers x 12 KB: [0,4 KB) data f32 [t16][ch64]; [4,12 KB) basis bf16
    __shared__ __align__(16) unsigned int lds32[3][3072];   // 36 KB

    const int tid  = threadIdx.x;
    const int lane = tid & 63;
    const int wv   = __builtin_amdgcn_readfirstlane(tid >> 6);
    const int wm   = wv >> 1, wc = wv & 1;   // m-half, ch-half
    const int ml   = lane & 31;
    const int khl  = lane >> 5;

    const int srow = tid >> 4;     // staging: t row 0..15
    const int sc4  = tid & 15;     // f4 index within 64 ch
    const float* __restrict__ ap = src + (size_t)b * 2048 * 512 + chtile * 64;

    f32x16 accR, accI;
#pragma unroll
    for (int i = 0; i < 16; ++i) { accR[i] = 0.f; accI[i] = 0.f; }

#define STAGE(BF, C)                                                          \
    {                                                                         \
        unsigned int* db = &lds32[BF][0];                                     \
        gl_lds16(ap + (size_t)(part * 512 + (C) * 16 + srow) * 512 + sc4 * 4, \
                 db + wv * 256);                                              \
        const unsigned short* bch = basisF + (size_t)(part * 32 + (C)) * 4096;\
        gl_lds16(bch + (size_t)tid * 8,         db + 1024 + wv * 256);        \
        gl_lds16(bch + (size_t)(256 + tid) * 8, db + 2048 + wv * 256);        \
    }

#define COMP(BF)                                                              \
    {                                                                         \
        const float* dl = (const float*)&lds32[BF][0];                        \
        const unsigned short* bl = (const unsigned short*)&lds32[BF][1024];   \
        float a[8];                                                           \
        _Pragma("unroll")                                                     \
        for (int e = 0; e < 8; ++e)                                           \
            a[e] = dl[(khl * 8 + e) * 64 + wc * 32 + ml];                     \
        short8v uH, uL;                                                       \
        _Pragma("unroll")                                                     \
        for (int e = 0; e < 8; ++e) {                                         \
            unsigned short hi = bf16_rne(a[e]);                               \
            uH[e] = (short)hi;                                                \
            uL[e] = (short)bf16_rne(a[e] - bf16_f(hi));                       \
        }                                                                     \
        const unsigned short* bb = bl + khl * 512 + (wm * 32 + ml) * 8;       \
        short8v cH = *(const short8v*)(bb);                                   \
        short8v cL = *(const short8v*)(bb + 1024);                            \
        short8v sH = *(const short8v*)(bb + 2048);                            \
        short8v sL = *(const short8v*)(bb + 3072);                            \
        accR = __builtin_amdgcn_mfma_f32_32x32x16_bf16(cH, uH, accR, 0, 0, 0);\
        accR = __builtin_amdgcn_mfma_f32_32x32x16_bf16(cH, uL, accR, 0, 0, 0);\
        accR = __builtin_amdgcn_mfma_f32_32x32x16_bf16(cL, uH, accR, 0, 0, 0);\
        accI = __builtin_amdgcn_mfma_f32_32x32x16_bf16(sH, uH, accI, 0, 0, 0);\
        accI = __builtin_amdgcn_mfma_f32_32x32x16_bf16(sH, uL, accI, 0, 0, 0);\
        accI = __builtin_amdgcn_mfma_f32_32x32x16_bf16(sL, uH, accI, 0, 0, 0);\
    }

    // prologue: chunks 0..2 in flight (9 loads/wave outstanding)
    STAGE(0, 0);
    STAGE(1, 1);
    STAGE(2, 2);
    for (int c = 0; c < 29; ++c) {         // stages chunks 3..31 only
        const int bf = c % 3;
        asm volatile("s_waitcnt vmcnt(6)" ::: "memory");   // chunk c landed
        __builtin_amdgcn_sched_barrier(0);
        __builtin_amdgcn_s_barrier();      // chunk c visible to all waves
        COMP(bf);
        __builtin_amdgcn_s_barrier();      // all waves done reading buf c
        __builtin_amdgcn_sched_barrier(0);
        STAGE(bf, c + 3);                  // refill freed buffer
    }
    // c = 29 (buffer 2): chunks 30,31 outstanding after wait
    asm volatile("s_waitcnt vmcnt(6)" ::: "memory");
    __builtin_amdgcn_sched_barrier(0);
    __builtin_amdgcn_s_barrier();
    COMP(2);
    __builtin_amdgcn_s_barrier();
    // c = 30 (buffer 0)
    asm volatile("s_waitcnt vmcnt(3)" ::: "memory");
    __builtin_amdgcn_sched_barrier(0);
    __builtin_amdgcn_s_barrier();
    COMP(0);
    __builtin_amdgcn_s_barrier();
    // c = 31 (buffer 1)
    asm volatile("s_waitcnt vmcnt(0)" ::: "memory");
    __builtin_amdgcn_sched_barrier(0);
    __builtin_amdgcn_s_barrier();
    COMP(1);
#undef STAGE
#undef COMP

    // epilogue: XOR-swizzled LDS transpose (64m x 64ch fp32 = 16 KB) -> [p][h][m][e]
    float* LF = (float*)&lds32[0][0];
#pragma unroll 1
    for (int pass = 0; pass < 2; ++pass) {
        __syncthreads();
#pragma unroll
        for (int reg = 0; reg < 16; ++reg) {
            const int m = wm * 32 + (reg & 3) + 8 * (reg >> 2) + 4 * khl;
            const int chL = wc * 32 + ml;
            LF[m * 64 + (chL ^ ((m & 7) << 3))] = pass ? accI[reg] : accR[reg];
        }
        __syncthreads();
#pragma unroll
        for (int u8 = 0; u8 < 4; ++u8) {
            int unit = tid + u8 * 256;           // 1024 units = m64 x eh2 x h8
            int h = unit & 7, eh = (unit >> 3) & 1, m = unit >> 4;
            float4 val;
#pragma unroll
            for (int j = 0; j < 4; ++j) {
                int chL = (eh * 4 + j) * 8 + h;
                ((float*)&val)[j] = LF[m * 64 + (chL ^ ((m & 7) << 3))];
            }
            *(float4*)&xp[pass * 32768 + (h * 64 + m) * 64 + chtile * 8 + eh * 4] = val;
        }
    }
}

// Middle: per (b,h,x-half). S = Q K (complex), tanh, xqkv, scale -> YT (bf16 split, transposed)
__global__ __launch_bounds__(128) void mid_kernel(float* __restrict__ ws) {
    const int h = blockIdx.x, b = blockIdx.y, xh = blockIdx.z;
    unsigned short* __restrict__ YTb = (unsigned short*)ws + YT_U + (size_t)b * 131072;

    __shared__ float Qs[2][32][64];   // Q [xl][e]; reused as T [xl][y]
    __shared__ float Ksw[2][64][64];  // K [m][e] XOR-swizzled [m][e^m]

    const int tid = threadIdx.x;
    for (int slot = tid; slot < 1024; slot += 128) {   // p2 x 32m x 16f4
        int p = slot >> 9, ml = (slot >> 4) & 31, c4 = slot & 15;
        int off = ((p * 8 + h) * 64 + xh * 32 + ml) * 64 + c4 * 4;
        float4 acc = make_float4(0.f, 0.f, 0.f, 0.f);
#pragma unroll
        for (int part = 0; part < 4; ++part) {
            const float4 v = *(const float4*)(ws + XP_F + (size_t)(part * 16 + b) * 65536 + off);
            acc.x += v.x; acc.y += v.y; acc.z += v.z; acc.w += v.w;
        }
        *(float4*)(&Qs[p][ml][c4 * 4]) = acc;
    }
    for (int slot = tid; slot < 2048; slot += 128) {   // p2 x 64m x 16f4
        int p = slot >> 10, ml = (slot >> 4) & 63, c4 = slot & 15;
        int off = ((p * 8 + h) * 64 + ml) * 64 + c4 * 4;
        float4 acc = make_float4(0.f, 0.f, 0.f, 0.f);
#pragma unroll
        for (int part = 0; part < 4; ++part) {
            const float4 v = *(const float4*)(ws + XP_F + (size_t)((4 + part) * 16 + b) * 65536 + off);
            acc.x += v.x; acc.y += v.y; acc.z += v.z; acc.w += v.w;
        }
        Ksw[p][ml][(c4 * 4 + 0) ^ ml] = acc.x;
        Ksw[p][ml][(c4 * 4 + 1) ^ ml] = acc.y;
        Ksw[p][ml][(c4 * 4 + 2) ^ ml] = acc.z;
        Ksw[p][ml][(c4 * 4 + 3) ^ ml] = acc.w;
    }
    __syncthreads();

    const int lane = tid & 63;
    const int wid  = tid >> 6;
    const int xb   = wid * 16;

    float sr[16], si[16];
#pragma unroll
    for (int i = 0; i < 16; ++i) { sr[i] = 0.f; si[i] = 0.f; }
    const int y = lane;
    for (int e = 0; e < 64; ++e) {
        float kr = Ksw[0][y][e ^ y];
        float ki = Ksw[1][y][e ^ y];
#pragma unroll
        for (int i = 0; i < 16; ++i) {
            float qr = Qs[0][xb + i][e];
            float qi = Qs[1][xb + i][e];
            sr[i] += qr * kr; sr[i] -= qi * ki;
            si[i] += qr * ki; si[i] += qi * kr;
        }
    }
    float tr[16], ti[16];
#pragma unroll
    for (int i = 0; i < 16; ++i) { tr[i] = tanhf(sr[i]); ti[i] = tanhf(si[i]); }
    __syncthreads();
#pragma unroll
    for (int i = 0; i < 16; ++i) {
        Qs[0][xb + i][y] = tr[i];
        Qs[1][xb + i][y] = ti[i];
    }
    __syncthreads();

    float vr[16], vi[16];
#pragma unroll
    for (int i = 0; i < 16; ++i) { vr[i] = 0.f; vi[i] = 0.f; }
    const int e = lane;
    for (int yy = 0; yy < 64; ++yy) {
        float kr = Ksw[0][yy][e ^ yy];
        float ki = Ksw[1][yy][e ^ yy];
#pragma unroll
        for (int i = 0; i < 16; ++i) {
            float trr = Qs[0][xb + i][yy];
            float tii = Qs[1][xb + i][yy];
            vr[i] += trr * kr; vr[i] -= tii * ki;
            vi[i] += trr * ki; vi[i] += tii * kr;
        }
    }
#pragma unroll
    for (int i = 0; i < 16; ++i) {
        int x = xh * 32 + xb + i;
        float f = (x == 0 ? 1.0f : 2.0f) * (1.0f / (2048.0f * 4096.0f));
        float yr = f * vr[i];
        float yi = -f * vi[i];     // sign folded: out = P + Q with +sin table
        int off = (h * 64 + e) * 64 + x;
        unsigned short rH = bf16_rne(yr), iH = bf16_rne(yi);
        YTb[off]         = rH;
        YTb[32768 + off] = bf16_rne(yr - bf16_f(rH));
        YTb[65536 + off] = iH;
        YTb[98304 + off] = bf16_rne(yi - bf16_f(iH));
    }
}

// Inverse folded DFT via bf16-split MFMA. Block: 64t x 128ch; 4 waves (wt2 x wcc2),
// wave = 32t x 64ch (2 accs/side). Y staged in LDS from YT (m-slabs of 16, dbuf).
// P=sum cos*Yr, Q=sum sin*Yi; out[t]=P+Q (t<=1024), out[2048-t]=P-Q (1<=t<=1023).
__global__ __launch_bounds__(256, 3) void idft_kernel(const float* __restrict__ ws,
                                                      float* __restrict__ out) {
    const int tt0    = blockIdx.x * 64;   // 0..1024
    const int chtile = blockIdx.y;        // 0..3
    const int b      = blockIdx.z;
    const unsigned short* __restrict__ basisI = (const unsigned short*)ws + BI_U;
    const unsigned short* __restrict__ YTb = (const unsigned short*)ws + YT_U + (size_t)b * 131072;

    // [tbl4][ch128][24] per buffer = 12288 ushorts (stride 24 for alignment + banks)
    __shared__ __align__(16) unsigned short ldsY[2][12288];   // 48 KB

    const int tid  = threadIdx.x;
    const int lane = tid & 63;
    const int wv   = tid >> 6;
    const int wt   = wv >> 1, wcc = wv & 1;
    const int ml   = lane & 31;
    const int khl  = lane >> 5;

    f32x16 accP0, accP1, accQ0, accQ1;
#pragma unroll
    for (int i = 0; i < 16; ++i) { accP0[i] = 0.f; accP1[i] = 0.f; accQ0[i] = 0.f; accQ1[i] = 0.f; }

    const int tblA = tid >> 7;            // staging row A: tables 0,1
    const int chlA = tid & 127;
    short8v sA0, sA1, sB0, sB1;

    auto LOAD = [&](int s) {
        const unsigned short* gA = YTb + tblA * 32768 + (chtile * 128 + chlA) * 64 + s * 16;
        const unsigned short* gB = gA + 2 * 32768;      // tables 2,3
        sA0 = *(const short8v*)(gA);
        sA1 = *(const short8v*)(gA + 8);
        sB0 = *(const short8v*)(gB);
        sB1 = *(const short8v*)(gB + 8);
    };
    auto WRITE = [&](int bf) {
        unsigned short* D = &ldsY[bf][0];
        const int offA = tblA * 3072 + chlA * 24;
        *(short8v*)(D + offA)            = sA0;
        *(short8v*)(D + offA + 8)        = sA1;
        *(short8v*)(D + offA + 2 * 3072)     = sB0;
        *(short8v*)(D + offA + 2 * 3072 + 8) = sB1;
    };
    auto COMP = [&](int bf, int s) {
        const unsigned short* bb = basisI + (s * 8 + khl) * 8704 + (tt0 + wt * 32 + ml) * 8;
        short8v cH = *(const short8v*)(bb);
        short8v cL = *(const short8v*)(bb + 17408);
        short8v sH = *(const short8v*)(bb + 34816);
        short8v sL = *(const short8v*)(bb + 52224);
        const unsigned short* L = &ldsY[bf][0];
        const int b0 = (wcc * 64 + ml) * 24 + khl * 8;
        short8v yrH0 = *(const short8v*)(L + b0);
        short8v yrL0 = *(const short8v*)(L + 3072 + b0);
        short8v yiH0 = *(const short8v*)(L + 6144 + b0);
        short8v yiL0 = *(const short8v*)(L + 9216 + b0);
        const int b1 = b0 + 32 * 24;
        short8v yrH1 = *(const short8v*)(L + b1);
        short8v yrL1 = *(const short8v*)(L + 3072 + b1);
        short8v yiH1 = *(const short8v*)(L + 6144 + b1);
        short8v yiL1 = *(const short8v*)(L + 9216 + b1);
        accP0 = __builtin_amdgcn_mfma_f32_32x32x16_bf16(cH, yrH0, accP0, 0, 0, 0);
        accP0 = __builtin_amdgcn_mfma_f32_32x32x16_bf16(cH, yrL0, accP0, 0, 0, 0);
        accP0 = __builtin_amdgcn_mfma_f32_32x32x16_bf16(cL, yrH0, accP0, 0, 0, 0);
        accQ0 = __builtin_amdgcn_mfma_f32_32x32x16_bf16(sH, yiH0, accQ0, 0, 0, 0);
        accQ0 = __builtin_amdgcn_mfma_f32_32x32x16_bf16(sH, yiL0, accQ0, 0, 0, 0);
        accQ0 = __builtin_amdgcn_mfma_f32_32x32x16_bf16(sL, yiH0, accQ0, 0, 0, 0);
        accP1 = __builtin_amdgcn_mfma_f32_32x32x16_bf16(cH, yrH1, accP1, 0, 0, 0);
        accP1 = __builtin_amdgcn_mfma_f32_32x32x16_bf16(cH, yrL1, accP1, 0, 0, 0);
        accP1 = __builtin_amdgcn_mfma_f32_32x32x16_bf16(cL, yrH1, accP1, 0, 0, 0);
        accQ1 = __builtin_amdgcn_mfma_f32_32x32x16_bf16(sH, yiH1, accQ1, 0, 0, 0);
        accQ1 = __builtin_amdgcn_mfma_f32_32x32x16_bf16(sH, yiL1, accQ1, 0, 0, 0);
        accQ1 = __builtin_amdgcn_mfma_f32_32x32x16_bf16(sL, yiH1, accQ1, 0, 0, 0);
    };

    LOAD(0); WRITE(0); __syncthreads();
    for (int s = 0; s < 4; ++s) {
        if (s < 3) LOAD(s + 1);
        COMP(s & 1, s);
        if (s < 3) { WRITE((s + 1) & 1); __syncthreads(); }
    }

    float* __restrict__ ob = out + (size_t)b * 2048 * 512;
#pragma unroll
    for (int reg = 0; reg < 16; ++reg) {
        const int tL = wt * 32 + (reg & 3) + 8 * (reg >> 2) + 4 * khl;
        const int t  = tt0 + tL;
        const int ch0 = chtile * 128 + wcc * 64 + ml;
        float p0 = accP0[reg], q0 = accQ0[reg];
        float p1 = accP1[reg], q1 = accQ1[reg];
        if (t <= 1024) {
            ob[(size_t)t * 512 + ch0]      = p0 + q0;
            ob[(size_t)t * 512 + ch0 + 32] = p1 + q1;
        }
        if (t >= 1 && t <= 1023) {
            ob[(size_t)(2048 - t) * 512 + ch0]      = p0 - q0;
            ob[(size_t)(2048 - t) * 512 + ch0 + 32] = p1 - q1;
        }
    }
}

extern "C" void kernel_launch(void* const* d_in, const int* in_sizes, int n_in,
                              void* d_out, int out_size, void* d_ws, size_t ws_size,
                              hipStream_t stream) {
    const float* q = (const float*)d_in[0];
    const float* k = (const float*)d_in[1];
    float* ws = (float*)d_ws;      // ~39.4 MB used
    float* out = (float*)d_out;

    hipLaunchKernelGGL(basis_kernel, dim3(512), dim3(256), 0, stream, ws);
    hipLaunchKernelGGL(fdft_kernel, dim3(8, 16, 8), dim3(256), 0, stream, q, k, ws);
    hipLaunchKernelGGL(mid_kernel, dim3(8, 16, 2), dim3(128), 0, stream, ws);
    hipLaunchKernelGGL(idft_kernel, dim3(17, 4, 16), dim3(256), 0, stream, ws, out);
}

// Round 18
// 105.692 us; speedup vs baseline: 1.1235x; 1.1235x over previous
//
#include <hip/hip_runtime.h>
#include <math.h>

typedef __attribute__((ext_vector_type(8))) short short8v;   // 8 bf16
typedef __attribute__((ext_vector_type(16))) float f32x16;   // MFMA acc

// ws layout:
//  ushort offsets:
//   basisF (fdft) [cc128][tbl4][kh2][m64][e8]    @ u 0        (524288 u)
//     tbl: 0=cosHi 1=cosLo 2=(-sin)Hi 3=(-sin)Lo ; t = cc*16 + kh*8 + e
//   basisI (idft) [slab4][tbl4][kh2][t1088][e8]  @ u 524288   (278528 u)
//     tbl: 0=cosHi 1=cosLo 2=sinHi 3=sinLo ; m = slab*16 + kh*8 + e
//  float offsets:
//   XP [zz8][b16][p2][h8][m64][e64]              @ f 401408   (8388608 f)
//  ushort offsets:
//   YT [b16][tbl4][ch512][m64]                   @ u 17580032 (2097152 u)
//     tbl: 0=YrHi 1=YrLo 2=YiHi 3=YiLo (Yi sign-folded)
#define BF_U 0
#define BI_U 524288
#define XP_F 401408
#define YT_U 17580032

__device__ inline unsigned short bf16_rne(float x) {
    unsigned int u = __float_as_uint(x);
    u += 0x7FFFu + ((u >> 16) & 1u);
    return (unsigned short)(u >> 16);
}
__device__ inline float bf16_f(unsigned short h) {
    return __uint_as_float(((unsigned int)h) << 16);
}

// async global->LDS, 16 B per lane; l must be wave-uniform, g per-lane.
__device__ inline void gl_lds16(const void* g, void* l) {
    __builtin_amdgcn_global_load_lds(
        (const __attribute__((address_space(1))) unsigned int*)g,
        (__attribute__((address_space(3))) unsigned int*)l, 16, 0, 0);
}

__global__ __launch_bounds__(256) void basis_kernel(float* __restrict__ w) {
    int idx = blockIdx.x * 256 + threadIdx.x;
    const float th = 0.0030679615757712823f; // 2*pi/2048
    unsigned short* bw = (unsigned short*)w;
    if (idx < 131072) {          // fdft tables: t 0..2047, m 0..63
        int t = idx >> 6, m = idx & 63;
        int j = (m * t) & 2047;
        float s, c; sincosf(th * (float)j, &s, &c);
        float ns = -s;
        int cc = t >> 4, kh = (t >> 3) & 1, e = t & 7;
        int base = BF_U + cc * 4096 + kh * 512 + m * 8 + e;
        unsigned short chv = bf16_rne(c), shv = bf16_rne(ns);
        bw[base]        = chv;
        bw[base + 1024] = bf16_rne(c - bf16_f(chv));
        bw[base + 2048] = shv;
        bw[base + 3072] = bf16_rne(ns - bf16_f(shv));
    }
    if (idx < 69632) {           // idft tables
        int m = idx / 1088, t = idx - m * 1088;
        int j = (m * t) & 2047;
        float s, c; sincosf(th * (float)j, &s, &c);
        int slab = m >> 4, kh = (m >> 3) & 1, e = m & 7;
        int base = BI_U + (slab * 8 + kh) * 8704 + t * 8 + e;
        unsigned short chv = bf16_rne(c), shv = bf16_rne(s);
        bw[base]         = chv;
        bw[base + 17408] = bf16_rne(c - bf16_f(chv));
        bw[base + 34816] = shv;
        bw[base + 52224] = bf16_rne(s - bf16_f(shv));
    }
}

// Forward (UNFOLDED) DFT via bf16-split MFMA, global_load_lds staging, DEPTH-3
// triple-buffer pipeline with counted vmcnt. Block: 64m x 64ch x t-quarter;
// 4 waves = (m-half x ch-half). Grid (chtile8, b16, zz8) = 1024 blocks.
__global__ __launch_bounds__(256, 4) void fdft_kernel(const float* __restrict__ q,
                                                      const float* __restrict__ k,
                                                      float* __restrict__ ws) {
    const int chtile = blockIdx.x;        // 0..7 (64 ch)
    const int b      = blockIdx.y;
    const int zz     = blockIdx.z;        // tz*4 + part
    const int part   = zz & 3;
    const float* __restrict__ src = (zz >> 2) ? k : q;
    const unsigned short* __restrict__ basisF = (const unsigned short*)ws + BF_U;
    float* __restrict__ xp = ws + XP_F + (size_t)(zz * 16 + b) * 65536;

    // 3 buffers x 12 KB: [0,4 KB) data f32 [t16][ch64]; [4,12 KB) basis bf16
    __shared__ __align__(16) unsigned int lds32[3][3072];   // 36 KB

    const int tid  = threadIdx.x;
    const int lane = tid & 63;
    const int wv   = __builtin_amdgcn_readfirstlane(tid >> 6);
    const int wm   = wv >> 1, wc = wv & 1;   // m-half, ch-half
    const int ml   = lane & 31;
    const int khl  = lane >> 5;

    const int srow = tid >> 4;     // staging: t row 0..15
    const int sc4  = tid & 15;     // f4 index within 64 ch
    const float* __restrict__ ap = src + (size_t)b * 2048 * 512 + chtile * 64;

    f32x16 accR, accI;
#pragma unroll
    for (int i = 0; i < 16; ++i) { accR[i] = 0.f; accI[i] = 0.f; }

#define STAGE(BF, C)                                                          \
    {                                                                         \
        unsigned int* db = &lds32[BF][0];                                     \
        gl_lds16(ap + (size_t)(part * 512 + (C) * 16 + srow) * 512 + sc4 * 4, \
                 db + wv * 256);                                              \
        const unsigned short* bch = basisF + (size_t)(part * 32 + (C)) * 4096;\
        gl_lds16(bch + (size_t)tid * 8,         db + 1024 + wv * 256);        \
        gl_lds16(bch + (size_t)(256 + tid) * 8, db + 2048 + wv * 256);        \
    }

#define COMP(BF)                                                              \
    {                                                                         \
        const float* dl = (const float*)&lds32[BF][0];                        \
        const unsigned short* bl = (const unsigned short*)&lds32[BF][1024];   \
        float a[8];                                                           \
        _Pragma("unroll")                                                     \
        for (int e = 0; e < 8; ++e)                                           \
            a[e] = dl[(khl * 8 + e) * 64 + wc * 32 + ml];                     \
        short8v uH, uL;                                                       \
        _Pragma("unroll")                                                     \
        for (int e = 0; e < 8; ++e) {                                         \
            unsigned short hi = bf16_rne(a[e]);                               \
            uH[e] = (short)hi;                                                \
            uL[e] = (short)bf16_rne(a[e] - bf16_f(hi));                       \
        }                                                                     \
        const unsigned short* bb = bl + khl * 512 + (wm * 32 + ml) * 8;       \
        short8v cH = *(const short8v*)(bb);                                   \
        short8v cL = *(const short8v*)(bb + 1024);                            \
        short8v sH = *(const short8v*)(bb + 2048);                            \
        short8v sL = *(const short8v*)(bb + 3072);                            \
        accR = __builtin_amdgcn_mfma_f32_32x32x16_bf16(cH, uH, accR, 0, 0, 0);\
        accR = __builtin_amdgcn_mfma_f32_32x32x16_bf16(cH, uL, accR, 0, 0, 0);\
        accR = __builtin_amdgcn_mfma_f32_32x32x16_bf16(cL, uH, accR, 0, 0, 0);\
        accI = __builtin_amdgcn_mfma_f32_32x32x16_bf16(sH, uH, accI, 0, 0, 0);\
        accI = __builtin_amdgcn_mfma_f32_32x32x16_bf16(sH, uL, accI, 0, 0, 0);\
        accI = __builtin_amdgcn_mfma_f32_32x32x16_bf16(sL, uH, accI, 0, 0, 0);\
    }

    // prologue: chunks 0..2 in flight (9 loads/wave outstanding)
    STAGE(0, 0);
    STAGE(1, 1);
    STAGE(2, 2);
    for (int c = 0; c < 29; ++c) {         // stages chunks 3..31 only
        const int bf = c % 3;
        asm volatile("s_waitcnt vmcnt(6)" ::: "memory");   // chunk c landed
        __builtin_amdgcn_sched_barrier(0);
        __builtin_amdgcn_s_barrier();      // chunk c visible to all waves
        COMP(bf);
        __builtin_amdgcn_s_barrier();      // all waves done reading buf c
        __builtin_amdgcn_sched_barrier(0);
        STAGE(bf, c + 3);                  // refill freed buffer
    }
    // c = 29 (buffer 2): chunks 30,31 outstanding after wait
    asm volatile("s_waitcnt vmcnt(6)" ::: "memory");
    __builtin_amdgcn_sched_barrier(0);
    __builtin_amdgcn_s_barrier();
    COMP(2);
    __builtin_amdgcn_s_barrier();
    // c = 30 (buffer 0)
    asm volatile("s_waitcnt vmcnt(3)" ::: "memory");
    __builtin_amdgcn_sched_barrier(0);
    __builtin_amdgcn_s_barrier();
    COMP(0);
    __builtin_amdgcn_s_barrier();
    // c = 31 (buffer 1)
    asm volatile("s_waitcnt vmcnt(0)" ::: "memory");
    __builtin_amdgcn_sched_barrier(0);
    __builtin_amdgcn_s_barrier();
    COMP(1);
#undef STAGE
#undef COMP

    // epilogue: XOR-swizzled LDS transpose (64m x 64ch fp32 = 16 KB) -> [p][h][m][e]
    float* LF = (float*)&lds32[0][0];
#pragma unroll 1
    for (int pass = 0; pass < 2; ++pass) {
        __syncthreads();
#pragma unroll
        for (int reg = 0; reg < 16; ++reg) {
            const int m = wm * 32 + (reg & 3) + 8 * (reg >> 2) + 4 * khl;
            const int chL = wc * 32 + ml;
            LF[m * 64 + (chL ^ ((m & 7) << 3))] = pass ? accI[reg] : accR[reg];
        }
        __syncthreads();
#pragma unroll
        for (int u8 = 0; u8 < 4; ++u8) {
            int unit = tid + u8 * 256;           // 1024 units = m64 x eh2 x h8
            int h = unit & 7, eh = (unit >> 3) & 1, m = unit >> 4;
            float4 val;
#pragma unroll
            for (int j = 0; j < 4; ++j) {
                int chL = (eh * 4 + j) * 8 + h;
                ((float*)&val)[j] = LF[m * 64 + (chL ^ ((m & 7) << 3))];
            }
            *(float4*)&xp[pass * 32768 + (h * 64 + m) * 64 + chtile * 8 + eh * 4] = val;
        }
    }
}

// Middle: per (b,h,x-half). 256 thr = 4 waves (wave -> 8 x-rows).
// S = Q K (complex), tanh, xqkv, scale -> YT (bf16 split, transposed)
__global__ __launch_bounds__(256) void mid_kernel(float* __restrict__ ws) {
    const int h = blockIdx.x, b = blockIdx.y, xh = blockIdx.z;
    unsigned short* __restrict__ YTb = (unsigned short*)ws + YT_U + (size_t)b * 131072;

    __shared__ float Qs[2][32][64];   // Q [xl][e]; reused as T [xl][y]
    __shared__ float Ksw[2][64][64];  // K [m][e] XOR-swizzled [m][e^m]

    const int tid = threadIdx.x;
    for (int slot = tid; slot < 1024; slot += 256) {   // p2 x 32m x 16f4
        int p = slot >> 9, ml = (slot >> 4) & 31, c4 = slot & 15;
        int off = ((p * 8 + h) * 64 + xh * 32 + ml) * 64 + c4 * 4;
        float4 acc = make_float4(0.f, 0.f, 0.f, 0.f);
#pragma unroll
        for (int part = 0; part < 4; ++part) {
            const float4 v = *(const float4*)(ws + XP_F + (size_t)(part * 16 + b) * 65536 + off);
            acc.x += v.x; acc.y += v.y; acc.z += v.z; acc.w += v.w;
        }
        *(float4*)(&Qs[p][ml][c4 * 4]) = acc;
    }
    for (int slot = tid; slot < 2048; slot += 256) {   // p2 x 64m x 16f4
        int p = slot >> 10, ml = (slot >> 4) & 63, c4 = slot & 15;
        int off = ((p * 8 + h) * 64 + ml) * 64 + c4 * 4;
        float4 acc = make_float4(0.f, 0.f, 0.f, 0.f);
#pragma unroll
        for (int part = 0; part < 4; ++part) {
            const float4 v = *(const float4*)(ws + XP_F + (size_t)((4 + part) * 16 + b) * 65536 + off);
            acc.x += v.x; acc.y += v.y; acc.z += v.z; acc.w += v.w;
        }
        Ksw[p][ml][(c4 * 4 + 0) ^ ml] = acc.x;
        Ksw[p][ml][(c4 * 4 + 1) ^ ml] = acc.y;
        Ksw[p][ml][(c4 * 4 + 2) ^ ml] = acc.z;
        Ksw[p][ml][(c4 * 4 + 3) ^ ml] = acc.w;
    }
    __syncthreads();

    const int lane = tid & 63;
    const int wid  = tid >> 6;   // 0..3
    const int xb   = wid * 8;

    float sr[8], si[8];
#pragma unroll
    for (int i = 0; i < 8; ++i) { sr[i] = 0.f; si[i] = 0.f; }
    const int y = lane;
    for (int e = 0; e < 64; ++e) {
        float kr = Ksw[0][y][e ^ y];
        float ki = Ksw[1][y][e ^ y];
#pragma unroll
        for (int i = 0; i < 8; ++i) {
            float qr = Qs[0][xb + i][e];
            float qi = Qs[1][xb + i][e];
            sr[i] += qr * kr; sr[i] -= qi * ki;
            si[i] += qr * ki; si[i] += qi * kr;
        }
    }
    float tr[8], ti[8];
#pragma unroll
    for (int i = 0; i < 8; ++i) { tr[i] = tanhf(sr[i]); ti[i] = tanhf(si[i]); }
    __syncthreads();
#pragma unroll
    for (int i = 0; i < 8; ++i) {
        Qs[0][xb + i][y] = tr[i];
        Qs[1][xb + i][y] = ti[i];
    }
    __syncthreads();

    float vr[8], vi[8];
#pragma unroll
    for (int i = 0; i < 8; ++i) { vr[i] = 0.f; vi[i] = 0.f; }
    const int e = lane;
    for (int yy = 0; yy < 64; ++yy) {
        float kr = Ksw[0][yy][e ^ yy];
        float ki = Ksw[1][yy][e ^ yy];
#pragma unroll
        for (int i = 0; i < 8; ++i) {
            float trr = Qs[0][xb + i][yy];
            float tii = Qs[1][xb + i][yy];
            vr[i] += trr * kr; vr[i] -= tii * ki;
            vi[i] += trr * ki; vi[i] += tii * kr;
        }
    }
#pragma unroll
    for (int i = 0; i < 8; ++i) {
        int x = xh * 32 + xb + i;
        float f = (x == 0 ? 1.0f : 2.0f) * (1.0f / (2048.0f * 4096.0f));
        float yr = f * vr[i];
        float yi = -f * vi[i];     // sign folded: out = P + Q with +sin table
        int off = (h * 64 + e) * 64 + x;
        unsigned short rH = bf16_rne(yr), iH = bf16_rne(yi);
        YTb[off]         = rH;
        YTb[32768 + off] = bf16_rne(yr - bf16_f(rH));
        YTb[65536 + off] = iH;
        YTb[98304 + off] = bf16_rne(yi - bf16_f(iH));
    }
}

// Inverse folded DFT via bf16-split MFMA. Block: 64t x 128ch; 4 waves (wt2 x wcc2),
// wave = 32t x 64ch (2 accs/side). Y staged in LDS from YT (m-slabs of 16, dbuf).
// P=sum cos*Yr, Q=sum sin*Yi; out[t]=P+Q (t<=1024), out[2048-t]=P-Q (1<=t<=1023).
__global__ __launch_bounds__(256, 3) void idft_kernel(const float* __restrict__ ws,
                                                      float* __restrict__ out) {
    const int tt0    = blockIdx.x * 64;   // 0..1024
    const int chtile = blockIdx.y;        // 0..3
    const int b      = blockIdx.z;
    const unsigned short* __restrict__ basisI = (const unsigned short*)ws + BI_U;
    const unsigned short* __restrict__ YTb = (const unsigned short*)ws + YT_U + (size_t)b * 131072;

    // [tbl4][ch128][24] per buffer = 12288 ushorts (stride 24 for alignment + banks)
    __shared__ __align__(16) unsigned short ldsY[2][12288];   // 48 KB

    const int tid  = threadIdx.x;
    const int lane = tid & 63;
    const int wv   = tid >> 6;
    const int wt   = wv >> 1, wcc = wv & 1;
    const int ml   = lane & 31;
    const int khl  = lane >> 5;

    f32x16 accP0, accP1, accQ0, accQ1;
#pragma unroll
    for (int i = 0; i < 16; ++i) { accP0[i] = 0.f; accP1[i] = 0.f; accQ0[i] = 0.f; accQ1[i] = 0.f; }

    const int tblA = tid >> 7;            // staging row A: tables 0,1
    const int chlA = tid & 127;
    short8v sA0, sA1, sB0, sB1;

    auto LOAD = [&](int s) {
        const unsigned short* gA = YTb + tblA * 32768 + (chtile * 128 + chlA) * 64 + s * 16;
        const unsigned short* gB = gA + 2 * 32768;      // tables 2,3
        sA0 = *(const short8v*)(gA);
        sA1 = *(const short8v*)(gA + 8);
        sB0 = *(const short8v*)(gB);
        sB1 = *(const short8v*)(gB + 8);
    };
    auto WRITE = [&](int bf) {
        unsigned short* D = &ldsY[bf][0];
        const int offA = tblA * 3072 + chlA * 24;
        *(short8v*)(D + offA)            = sA0;
        *(short8v*)(D + offA + 8)        = sA1;
        *(short8v*)(D + offA + 2 * 3072)     = sB0;
        *(short8v*)(D + offA + 2 * 3072 + 8) = sB1;
    };
    auto COMP = [&](int bf, int s) {
        const unsigned short* bb = basisI + (s * 8 + khl) * 8704 + (tt0 + wt * 32 + ml) * 8;
        short8v cH = *(const short8v*)(bb);
        short8v cL = *(const short8v*)(bb + 17408);
        short8v sH = *(const short8v*)(bb + 34816);
        short8v sL = *(const short8v*)(bb + 52224);
        const unsigned short* L = &ldsY[bf][0];
        const int b0 = (wcc * 64 + ml) * 24 + khl * 8;
        short8v yrH0 = *(const short8v*)(L + b0);
        short8v yrL0 = *(const short8v*)(L + 3072 + b0);
        short8v yiH0 = *(const short8v*)(L + 6144 + b0);
        short8v yiL0 = *(const short8v*)(L + 9216 + b0);
        const int b1 = b0 + 32 * 24;
        short8v yrH1 = *(const short8v*)(L + b1);
        short8v yrL1 = *(const short8v*)(L + 3072 + b1);
        short8v yiH1 = *(const short8v*)(L + 6144 + b1);
        short8v yiL1 = *(const short8v*)(L + 9216 + b1);
        accP0 = __builtin_amdgcn_mfma_f32_32x32x16_bf16(cH, yrH0, accP0, 0, 0, 0);
        accP0 = __builtin_amdgcn_mfma_f32_32x32x16_bf16(cH, yrL0, accP0, 0, 0, 0);
        accP0 = __builtin_amdgcn_mfma_f32_32x32x16_bf16(cL, yrH0, accP0, 0, 0, 0);
        accQ0 = __builtin_amdgcn_mfma_f32_32x32x16_bf16(sH, yiH0, accQ0, 0, 0, 0);
        accQ0 = __builtin_amdgcn_mfma_f32_32x32x16_bf16(sH, yiL0, accQ0, 0, 0, 0);
        accQ0 = __builtin_amdgcn_mfma_f32_32x32x16_bf16(sL, yiH0, accQ0, 0, 0, 0);
        accP1 = __builtin_amdgcn_mfma_f32_32x32x16_bf16(cH, yrH1, accP1, 0, 0, 0);
        accP1 = __builtin_amdgcn_mfma_f32_32x32x16_bf16(cH, yrL1, accP1, 0, 0, 0);
        accP1 = __builtin_amdgcn_mfma_f32_32x32x16_bf16(cL, yrH1, accP1, 0, 0, 0);
        accQ1 = __builtin_amdgcn_mfma_f32_32x32x16_bf16(sH, yiH1, accQ1, 0, 0, 0);
        accQ1 = __builtin_amdgcn_mfma_f32_32x32x16_bf16(sH, yiL1, accQ1, 0, 0, 0);
        accQ1 = __builtin_amdgcn_mfma_f32_32x32x16_bf16(sL, yiH1, accQ1, 0, 0, 0);
    };

    LOAD(0); WRITE(0); __syncthreads();
    for (int s = 0; s < 4; ++s) {
        if (s < 3) LOAD(s + 1);
        COMP(s & 1, s);
        if (s < 3) { WRITE((s + 1) & 1); __syncthreads(); }
    }

    float* __restrict__ ob = out + (size_t)b * 2048 * 512;
#pragma unroll
    for (int reg = 0; reg < 16; ++reg) {
        const int tL = wt * 32 + (reg & 3) + 8 * (reg >> 2) + 4 * khl;
        const int t  = tt0 + tL;
        const int ch0 = chtile * 128 + wcc * 64 + ml;
        float p0 = accP0[reg], q0 = accQ0[reg];
        float p1 = accP1[reg], q1 = accQ1[reg];
        if (t <= 1024) {
            ob[(size_t)t * 512 + ch0]      = p0 + q0;
            ob[(size_t)t * 512 + ch0 + 32] = p1 + q1;
        }
        if (t >= 1 && t <= 1023) {
            ob[(size_t)(2048 - t) * 512 + ch0]      = p0 - q0;
            ob[(size_t)(2048 - t) * 512 + ch0 + 32] = p1 - q1;
        }
    }
}

extern "C" void kernel_launch(void* const* d_in, const int* in_sizes, int n_in,
                              void* d_out, int out_size, void* d_ws, size_t ws_size,
                              hipStream_t stream) {
    const float* q = (const float*)d_in[0];
    const float* k = (const float*)d_in[1];
    float* ws = (float*)d_ws;      // ~39.4 MB used
    float* out = (float*)d_out;

    hipLaunchKernelGGL(basis_kernel, dim3(512), dim3(256), 0, stream, ws);
    hipLaunchKernelGGL(fdft_kernel, dim3(8, 16, 8), dim3(256), 0, stream, q, k, ws);
    hipLaunchKernelGGL(mid_kernel, dim3(8, 16, 2), dim3(256), 0, stream, ws);
    hipLaunchKernelGGL(idft_kernel, dim3(17, 4, 16), dim3(256), 0, stream, ws, out);
}

// Round 19
// 104.220 us; speedup vs baseline: 1.1394x; 1.0141x over previous
//
#include <hip/hip_runtime.h>
#include <math.h>

typedef __attribute__((ext_vector_type(8))) short short8v;   // 8 bf16
typedef __attribute__((ext_vector_type(16))) float f32x16;   // MFMA acc

// ws layout:
//  ushort offsets:
//   basisF (fdft) [cc128][tbl4][kh2][m64][e8]    @ u 0        (524288 u)
//     tbl: 0=cosHi 1=cosLo 2=(-sin)Hi 3=(-sin)Lo ; t = cc*16 + kh*8 + e
//   basisI (idft) [slab4][tbl4][kh2][t1088][e8]  @ u 524288   (278528 u)
//     tbl: 0=cosHi 1=cosLo 2=sinHi 3=sinLo ; m = slab*16 + kh*8 + e
//  float offsets:
//   XP [zz8][b16][p2][h8][m64][e64]              @ f 401408   (8388608 f)
//  ushort offsets:
//   YT [b16][tbl4][ch512][m64]                   @ u 17580032 (2097152 u)
//     tbl: 0=YrHi 1=YrLo 2=YiHi 3=YiLo (Yi sign-folded)
#define BF_U 0
#define BI_U 524288
#define XP_F 401408
#define YT_U 17580032

__device__ inline unsigned short bf16_rne(float x) {
    unsigned int u = __float_as_uint(x);
    u += 0x7FFFu + ((u >> 16) & 1u);
    return (unsigned short)(u >> 16);
}
__device__ inline float bf16_f(unsigned short h) {
    return __uint_as_float(((unsigned int)h) << 16);
}

// async global->LDS, 16 B per lane; l must be wave-uniform, g per-lane.
__device__ inline void gl_lds16(const void* g, void* l) {
    __builtin_amdgcn_global_load_lds(
        (const __attribute__((address_space(1))) unsigned int*)g,
        (__attribute__((address_space(3))) unsigned int*)l, 16, 0, 0);
}

__global__ __launch_bounds__(256) void basis_kernel(float* __restrict__ w) {
    int idx = blockIdx.x * 256 + threadIdx.x;
    const float th = 0.0030679615757712823f; // 2*pi/2048
    unsigned short* bw = (unsigned short*)w;
    if (idx < 131072) {          // fdft tables: t 0..2047, m 0..63
        int t = idx >> 6, m = idx & 63;
        int j = (m * t) & 2047;
        float s, c; sincosf(th * (float)j, &s, &c);
        float ns = -s;
        int cc = t >> 4, kh = (t >> 3) & 1, e = t & 7;
        int base = BF_U + cc * 4096 + kh * 512 + m * 8 + e;
        unsigned short chv = bf16_rne(c), shv = bf16_rne(ns);
        bw[base]        = chv;
        bw[base + 1024] = bf16_rne(c - bf16_f(chv));
        bw[base + 2048] = shv;
        bw[base + 3072] = bf16_rne(ns - bf16_f(shv));
    }
    if (idx < 69632) {           // idft tables
        int m = idx / 1088, t = idx - m * 1088;
        int j = (m * t) & 2047;
        float s, c; sincosf(th * (float)j, &s, &c);
        int slab = m >> 4, kh = (m >> 3) & 1, e = m & 7;
        int base = BI_U + (slab * 8 + kh) * 8704 + t * 8 + e;
        unsigned short chv = bf16_rne(c), shv = bf16_rne(s);
        bw[base]         = chv;
        bw[base + 17408] = bf16_rne(c - bf16_f(chv));
        bw[base + 34816] = shv;
        bw[base + 52224] = bf16_rne(s - bf16_f(shv));
    }
}

// Forward (UNFOLDED) DFT via bf16-split MFMA. DATA: global_load_lds depth-3
// triple-buffer with counted vmcnt (1 DMA/chunk). BASIS: direct global b128
// reads inside COMP (L2-hot, compiler-scheduled) — no LDS round trip.
// Block: 64m x 64ch x t-quarter; 4 waves = (m-half x ch-half).
// Grid (chtile8, b16, zz8) = 1024 blocks.
__global__ __launch_bounds__(256, 4) void fdft_kernel(const float* __restrict__ q,
                                                      const float* __restrict__ k,
                                                      float* __restrict__ ws) {
    const int chtile = blockIdx.x;        // 0..7 (64 ch)
    const int b      = blockIdx.y;
    const int zz     = blockIdx.z;        // tz*4 + part
    const int part   = zz & 3;
    const float* __restrict__ src = (zz >> 2) ? k : q;
    const unsigned short* __restrict__ basisF = (const unsigned short*)ws + BF_U;
    float* __restrict__ xp = ws + XP_F + (size_t)(zz * 16 + b) * 65536;

    // 16 KB: 3 data buffers of 1024 u32 (4 KB each); whole array reused by epilogue
    __shared__ __align__(16) unsigned int lds32[4096];

    const int tid  = threadIdx.x;
    const int lane = tid & 63;
    const int wv   = __builtin_amdgcn_readfirstlane(tid >> 6);
    const int wm   = wv >> 1, wc = wv & 1;   // m-half, ch-half
    const int ml   = lane & 31;
    const int khl  = lane >> 5;

    const int srow = tid >> 4;     // staging: t row 0..15
    const int sc4  = tid & 15;     // f4 index within 64 ch
    const float* __restrict__ ap = src + (size_t)b * 2048 * 512 + chtile * 64;

    f32x16 accR, accI;
#pragma unroll
    for (int i = 0; i < 16; ++i) { accR[i] = 0.f; accI[i] = 0.f; }

#define STAGE(BF, C)                                                          \
    gl_lds16(ap + (size_t)(part * 512 + (C) * 16 + srow) * 512 + sc4 * 4,     \
             lds32 + (BF) * 1024 + wv * 256);

#define COMP(BF, C)                                                           \
    {                                                                         \
        const float* dl = (const float*)(lds32 + (BF) * 1024);                \
        float a[8];                                                           \
        _Pragma("unroll")                                                     \
        for (int e = 0; e < 8; ++e)                                           \
            a[e] = dl[(khl * 8 + e) * 64 + wc * 32 + ml];                     \
        short8v uH, uL;                                                       \
        _Pragma("unroll")                                                     \
        for (int e = 0; e < 8; ++e) {                                         \
            unsigned short hi = bf16_rne(a[e]);                               \
            uH[e] = (short)hi;                                                \
            uL[e] = (short)bf16_rne(a[e] - bf16_f(hi));                       \
        }                                                                     \
        const unsigned short* bb = basisF + (size_t)(part * 32 + (C)) * 4096  \
                                 + khl * 512 + (wm * 32 + ml) * 8;            \
        short8v cH = *(const short8v*)(bb);                                   \
        short8v cL = *(const short8v*)(bb + 1024);                            \
        short8v sH = *(const short8v*)(bb + 2048);                            \
        short8v sL = *(const short8v*)(bb + 3072);                            \
        accR = __builtin_amdgcn_mfma_f32_32x32x16_bf16(cH, uH, accR, 0, 0, 0);\
        accR = __builtin_amdgcn_mfma_f32_32x32x16_bf16(cH, uL, accR, 0, 0, 0);\
        accR = __builtin_amdgcn_mfma_f32_32x32x16_bf16(cL, uH, accR, 0, 0, 0);\
        accI = __builtin_amdgcn_mfma_f32_32x32x16_bf16(sH, uH, accI, 0, 0, 0);\
        accI = __builtin_amdgcn_mfma_f32_32x32x16_bf16(sH, uL, accI, 0, 0, 0);\
        accI = __builtin_amdgcn_mfma_f32_32x32x16_bf16(sL, uH, accI, 0, 0, 0);\
    }

    // prologue: data chunks 0..2 in flight (3 DMA loads/wave outstanding)
    STAGE(0, 0);
    STAGE(1, 1);
    STAGE(2, 2);
    for (int c = 0; c < 29; ++c) {         // stages chunks 3..31 only
        const int bf = c % 3;
        // data chunk c landed; c+1, c+2 may stay in flight (basis loads only
        // make this wait stricter, never looser — safe)
        asm volatile("s_waitcnt vmcnt(2)" ::: "memory");
        __builtin_amdgcn_sched_barrier(0);
        __builtin_amdgcn_s_barrier();      // chunk c visible to all waves
        COMP(bf, c);
        __builtin_amdgcn_s_barrier();      // all waves done reading buf c
        __builtin_amdgcn_sched_barrier(0);
        STAGE(bf, c + 3);                  // refill freed buffer
    }
    // c = 29 (buffer 2): data 30,31 may remain
    asm volatile("s_waitcnt vmcnt(2)" ::: "memory");
    __builtin_amdgcn_sched_barrier(0);
    __builtin_amdgcn_s_barrier();
    COMP(2, 29);
    __builtin_amdgcn_s_barrier();
    // c = 30 (buffer 0)
    asm volatile("s_waitcnt vmcnt(1)" ::: "memory");
    __builtin_amdgcn_sched_barrier(0);
    __builtin_amdgcn_s_barrier();
    COMP(0, 30);
    __builtin_amdgcn_s_barrier();
    // c = 31 (buffer 1)
    asm volatile("s_waitcnt vmcnt(0)" ::: "memory");
    __builtin_amdgcn_sched_barrier(0);
    __builtin_amdgcn_s_barrier();
    COMP(1, 31);
#undef STAGE
#undef COMP

    // epilogue: XOR-swizzled LDS transpose (64m x 64ch fp32 = 16 KB) -> [p][h][m][e]
    float* LF = (float*)lds32;
#pragma unroll 1
    for (int pass = 0; pass < 2; ++pass) {
        __syncthreads();
#pragma unroll
        for (int reg = 0; reg < 16; ++reg) {
            const int m = wm * 32 + (reg & 3) + 8 * (reg >> 2) + 4 * khl;
            const int chL = wc * 32 + ml;
            LF[m * 64 + (chL ^ ((m & 7) << 3))] = pass ? accI[reg] : accR[reg];
        }
        __syncthreads();
#pragma unroll
        for (int u8 = 0; u8 < 4; ++u8) {
            int unit = tid + u8 * 256;           // 1024 units = m64 x eh2 x h8
            int h = unit & 7, eh = (unit >> 3) & 1, m = unit >> 4;
            float4 val;
#pragma unroll
            for (int j = 0; j < 4; ++j) {
                int chL = (eh * 4 + j) * 8 + h;
                ((float*)&val)[j] = LF[m * 64 + (chL ^ ((m & 7) << 3))];
            }
            *(float4*)&xp[pass * 32768 + (h * 64 + m) * 64 + chtile * 8 + eh * 4] = val;
        }
    }
}

// Middle: per (b,h,x-half). 256 thr = 4 waves (wave -> 8 x-rows).
// S = Q K (complex), tanh, xqkv, scale -> YT (bf16 split, transposed)
__global__ __launch_bounds__(256) void mid_kernel(float* __restrict__ ws) {
    const int h = blockIdx.x, b = blockIdx.y, xh = blockIdx.z;
    unsigned short* __restrict__ YTb = (unsigned short*)ws + YT_U + (size_t)b * 131072;

    __shared__ float Qs[2][32][64];   // Q [xl][e]; reused as T [xl][y]
    __shared__ float Ksw[2][64][64];  // K [m][e] XOR-swizzled [m][e^m]

    const int tid = threadIdx.x;
    for (int slot = tid; slot < 1024; slot += 256) {   // p2 x 32m x 16f4
        int p = slot >> 9, ml = (slot >> 4) & 31, c4 = slot & 15;
        int off = ((p * 8 + h) * 64 + xh * 32 + ml) * 64 + c4 * 4;
        float4 acc = make_float4(0.f, 0.f, 0.f, 0.f);
#pragma unroll
        for (int part = 0; part < 4; ++part) {
            const float4 v = *(const float4*)(ws + XP_F + (size_t)(part * 16 + b) * 65536 + off);
            acc.x += v.x; acc.y += v.y; acc.z += v.z; acc.w += v.w;
        }
        *(float4*)(&Qs[p][ml][c4 * 4]) = acc;
    }
    for (int slot = tid; slot < 2048; slot += 256) {   // p2 x 64m x 16f4
        int p = slot >> 10, ml = (slot >> 4) & 63, c4 = slot & 15;
        int off = ((p * 8 + h) * 64 + ml) * 64 + c4 * 4;
        float4 acc = make_float4(0.f, 0.f, 0.f, 0.f);
#pragma unroll
        for (int part = 0; part < 4; ++part) {
            const float4 v = *(const float4*)(ws + XP_F + (size_t)((4 + part) * 16 + b) * 65536 + off);
            acc.x += v.x; acc.y += v.y; acc.z += v.z; acc.w += v.w;
        }
        Ksw[p][ml][(c4 * 4 + 0) ^ ml] = acc.x;
        Ksw[p][ml][(c4 * 4 + 1) ^ ml] = acc.y;
        Ksw[p][ml][(c4 * 4 + 2) ^ ml] = acc.z;
        Ksw[p][ml][(c4 * 4 + 3) ^ ml] = acc.w;
    }
    __syncthreads();

    const int lane = tid & 63;
    const int wid  = tid >> 6;   // 0..3
    const int xb   = wid * 8;

    float sr[8], si[8];
#pragma unroll
    for (int i = 0; i < 8; ++i) { sr[i] = 0.f; si[i] = 0.f; }
    const int y = lane;
    for (int e = 0; e < 64; ++e) {
        float kr = Ksw[0][y][e ^ y];
        float ki = Ksw[1][y][e ^ y];
#pragma unroll
        for (int i = 0; i < 8; ++i) {
            float qr = Qs[0][xb + i][e];
            float qi = Qs[1][xb + i][e];
            sr[i] += qr * kr; sr[i] -= qi * ki;
            si[i] += qr * ki; si[i] += qi * kr;
        }
    }
    float tr[8], ti[8];
#pragma unroll
    for (int i = 0; i < 8; ++i) { tr[i] = tanhf(sr[i]); ti[i] = tanhf(si[i]); }
    __syncthreads();
#pragma unroll
    for (int i = 0; i < 8; ++i) {
        Qs[0][xb + i][y] = tr[i];
        Qs[1][xb + i][y] = ti[i];
    }
    __syncthreads();

    float vr[8], vi[8];
#pragma unroll
    for (int i = 0; i < 8; ++i) { vr[i] = 0.f; vi[i] = 0.f; }
    const int e = lane;
    for (int yy = 0; yy < 64; ++yy) {
        float kr = Ksw[0][yy][e ^ yy];
        float ki = Ksw[1][yy][e ^ yy];
#pragma unroll
        for (int i = 0; i < 8; ++i) {
            float trr = Qs[0][xb + i][yy];
            float tii = Qs[1][xb + i][yy];
            vr[i] += trr * kr; vr[i] -= tii * ki;
            vi[i] += trr * ki; vi[i] += tii * kr;
        }
    }
#pragma unroll
    for (int i = 0; i < 8; ++i) {
        int x = xh * 32 + xb + i;
        float f = (x == 0 ? 1.0f : 2.0f) * (1.0f / (2048.0f * 4096.0f));
        float yr = f * vr[i];
        float yi = -f * vi[i];     // sign folded: out = P + Q with +sin table
        int off = (h * 64 + e) * 64 + x;
        unsigned short rH = bf16_rne(yr), iH = bf16_rne(yi);
        YTb[off]         = rH;
        YTb[32768 + off] = bf16_rne(yr - bf16_f(rH));
        YTb[65536 + off] = iH;
        YTb[98304 + off] = bf16_rne(yi - bf16_f(iH));
    }
}

// Inverse folded DFT via bf16-split MFMA. Block: 64t x 128ch; 4 waves (wt2 x wcc2),
// wave = 32t x 64ch (2 accs/side). Y staged in LDS from YT (m-slabs of 16, dbuf).
// P=sum cos*Yr, Q=sum sin*Yi; out[t]=P+Q (t<=1024), out[2048-t]=P-Q (1<=t<=1023).
__global__ __launch_bounds__(256, 3) void idft_kernel(const float* __restrict__ ws,
                                                      float* __restrict__ out) {
    const int tt0    = blockIdx.x * 64;   // 0..1024
    const int chtile = blockIdx.y;        // 0..3
    const int b      = blockIdx.z;
    const unsigned short* __restrict__ basisI = (const unsigned short*)ws + BI_U;
    const unsigned short* __restrict__ YTb = (const unsigned short*)ws + YT_U + (size_t)b * 131072;

    // [tbl4][ch128][24] per buffer = 12288 ushorts (stride 24 for alignment + banks)
    __shared__ __align__(16) unsigned short ldsY[2][12288];   // 48 KB

    const int tid  = threadIdx.x;
    const int lane = tid & 63;
    const int wv   = tid >> 6;
    const int wt   = wv >> 1, wcc = wv & 1;
    const int ml   = lane & 31;
    const int khl  = lane >> 5;

    f32x16 accP0, accP1, accQ0, accQ1;
#pragma unroll
    for (int i = 0; i < 16; ++i) { accP0[i] = 0.f; accP1[i] = 0.f; accQ0[i] = 0.f; accQ1[i] = 0.f; }

    const int tblA = tid >> 7;            // staging row A: tables 0,1
    const int chlA = tid & 127;
    short8v sA0, sA1, sB0, sB1;

    auto LOAD = [&](int s) {
        const unsigned short* gA = YTb + tblA * 32768 + (chtile * 128 + chlA) * 64 + s * 16;
        const unsigned short* gB = gA + 2 * 32768;      // tables 2,3
        sA0 = *(const short8v*)(gA);
        sA1 = *(const short8v*)(gA + 8);
        sB0 = *(const short8v*)(gB);
        sB1 = *(const short8v*)(gB + 8);
    };
    auto WRITE = [&](int bf) {
        unsigned short* D = &ldsY[bf][0];
        const int offA = tblA * 3072 + chlA * 24;
        *(short8v*)(D + offA)            = sA0;
        *(short8v*)(D + offA + 8)        = sA1;
        *(short8v*)(D + offA + 2 * 3072)     = sB0;
        *(short8v*)(D + offA + 2 * 3072 + 8) = sB1;
    };
    auto COMP = [&](int bf, int s) {
        const unsigned short* bb = basisI + (s * 8 + khl) * 8704 + (tt0 + wt * 32 + ml) * 8;
        short8v cH = *(const short8v*)(bb);
        short8v cL = *(const short8v*)(bb + 17408);
        short8v sH = *(const short8v*)(bb + 34816);
        short8v sL = *(const short8v*)(bb + 52224);
        const unsigned short* L = &ldsY[bf][0];
        const int b0 = (wcc * 64 + ml) * 24 + khl * 8;
        short8v yrH0 = *(const short8v*)(L + b0);
        short8v yrL0 = *(const short8v*)(L + 3072 + b0);
        short8v yiH0 = *(const short8v*)(L + 6144 + b0);
        short8v yiL0 = *(const short8v*)(L + 9216 + b0);
        const int b1 = b0 + 32 * 24;
        short8v yrH1 = *(const short8v*)(L + b1);
        short8v yrL1 = *(const short8v*)(L + 3072 + b1);
        short8v yiH1 = *(const short8v*)(L + 6144 + b1);
        short8v yiL1 = *(const short8v*)(L + 9216 + b1);
        accP0 = __builtin_amdgcn_mfma_f32_32x32x16_bf16(cH, yrH0, accP0, 0, 0, 0);
        accP0 = __builtin_amdgcn_mfma_f32_32x32x16_bf16(cH, yrL0, accP0, 0, 0, 0);
        accP0 = __builtin_amdgcn_mfma_f32_32x32x16_bf16(cL, yrH0, accP0, 0, 0, 0);
        accQ0 = __builtin_amdgcn_mfma_f32_32x32x16_bf16(sH, yiH0, accQ0, 0, 0, 0);
        accQ0 = __builtin_amdgcn_mfma_f32_32x32x16_bf16(sH, yiL0, accQ0, 0, 0, 0);
        accQ0 = __builtin_amdgcn_mfma_f32_32x32x16_bf16(sL, yiH0, accQ0, 0, 0, 0);
        accP1 = __builtin_amdgcn_mfma_f32_32x32x16_bf16(cH, yrH1, accP1, 0, 0, 0);
        accP1 = __builtin_amdgcn_mfma_f32_32x32x16_bf16(cH, yrL1, accP1, 0, 0, 0);
        accP1 = __builtin_amdgcn_mfma_f32_32x32x16_bf16(cL, yrH1, accP1, 0, 0, 0);
        accQ1 = __builtin_amdgcn_mfma_f32_32x32x16_bf16(sH, yiH1, accQ1, 0, 0, 0);
        accQ1 = __builtin_amdgcn_mfma_f32_32x32x16_bf16(sH, yiL1, accQ1, 0, 0, 0);
        accQ1 = __builtin_amdgcn_mfma_f32_32x32x16_bf16(sL, yiH1, accQ1, 0, 0, 0);
    };

    LOAD(0); WRITE(0); __syncthreads();
    for (int s = 0; s < 4; ++s) {
        if (s < 3) LOAD(s + 1);
        COMP(s & 1, s);
        if (s < 3) { WRITE((s + 1) & 1); __syncthreads(); }
    }

    float* __restrict__ ob = out + (size_t)b * 2048 * 512;
#pragma unroll
    for (int reg = 0; reg < 16; ++reg) {
        const int tL = wt * 32 + (reg & 3) + 8 * (reg >> 2) + 4 * khl;
        const int t  = tt0 + tL;
        const int ch0 = chtile * 128 + wcc * 64 + ml;
        float p0 = accP0[reg], q0 = accQ0[reg];
        float p1 = accP1[reg], q1 = accQ1[reg];
        if (t <= 1024) {
            ob[(size_t)t * 512 + ch0]      = p0 + q0;
            ob[(size_t)t * 512 + ch0 + 32] = p1 + q1;
        }
        if (t >= 1 && t <= 1023) {
            ob[(size_t)(2048 - t) * 512 + ch0]      = p0 - q0;
            ob[(size_t)(2048 - t) * 512 + ch0 + 32] = p1 - q1;
        }
    }
}

extern "C" void kernel_launch(void* const* d_in, const int* in_sizes, int n_in,
                              void* d_out, int out_size, void* d_ws, size_t ws_size,
                              hipStream_t stream) {
    const float* q = (const float*)d_in[0];
    const float* k = (const float*)d_in[1];
    float* ws = (float*)d_ws;      // ~39.4 MB used
    float* out = (float*)d_out;

    hipLaunchKernelGGL(basis_kernel, dim3(512), dim3(256), 0, stream, ws);
    hipLaunchKernelGGL(fdft_kernel, dim3(8, 16, 8), dim3(256), 0, stream, q, k, ws);
    hipLaunchKernelGGL(mid_kernel, dim3(8, 16, 2), dim3(256), 0, stream, ws);
    hipLaunchKernelGGL(idft_kernel, dim3(17, 4, 16), dim3(256), 0, stream, ws, out);
}

// Round 20
// 102.032 us; speedup vs baseline: 1.1638x; 1.0214x over previous
//
#include <hip/hip_runtime.h>
#include <math.h>

typedef __attribute__((ext_vector_type(8))) short short8v;   // 8 bf16
typedef __attribute__((ext_vector_type(16))) float f32x16;   // MFMA acc

// ws layout:
//  ushort offsets:
//   basisF (fdft) [cc128][tbl4][kh2][m64][e8]    @ u 0        (524288 u)
//     tbl: 0=cosHi 1=cosLo 2=(-sin)Hi 3=(-sin)Lo ; t = cc*16 + kh*8 + e
//   basisI (idft) [slab4][tbl4][kh2][t1088][e8]  @ u 524288   (278528 u)
//     tbl: 0=cosHi 1=cosLo 2=sinHi 3=sinLo ; m = slab*16 + kh*8 + e
//  float offsets:
//   XP [zz8][b16][p2][h8][m64][e64]              @ f 401408   (8388608 f)
//  ushort offsets:
//   YT [b16][tbl4][ch512][m64]                   @ u 17580032 (2097152 u)
//     tbl: 0=YrHi 1=YrLo 2=YiHi 3=YiLo (Yi sign-folded)
#define BF_U 0
#define BI_U 524288
#define XP_F 401408
#define YT_U 17580032

__device__ inline unsigned short bf16_rne(float x) {
    unsigned int u = __float_as_uint(x);
    u += 0x7FFFu + ((u >> 16) & 1u);
    return (unsigned short)(u >> 16);
}
__device__ inline float bf16_f(unsigned short h) {
    return __uint_as_float(((unsigned int)h) << 16);
}

// async global->LDS, 16 B per lane; l must be wave-uniform, g per-lane.
__device__ inline void gl_lds16(const void* g, void* l) {
    __builtin_amdgcn_global_load_lds(
        (const __attribute__((address_space(1))) unsigned int*)g,
        (__attribute__((address_space(3))) unsigned int*)l, 16, 0, 0);
}

__global__ __launch_bounds__(256) void basis_kernel(float* __restrict__ w) {
    int idx = blockIdx.x * 256 + threadIdx.x;
    const float th = 0.0030679615757712823f; // 2*pi/2048
    unsigned short* bw = (unsigned short*)w;
    if (idx < 131072) {          // fdft tables: t 0..2047, m 0..63
        int t = idx >> 6, m = idx & 63;
        int j = (m * t) & 2047;
        float s, c; sincosf(th * (float)j, &s, &c);
        float ns = -s;
        int cc = t >> 4, kh = (t >> 3) & 1, e = t & 7;
        int base = BF_U + cc * 4096 + kh * 512 + m * 8 + e;
        unsigned short chv = bf16_rne(c), shv = bf16_rne(ns);
        bw[base]        = chv;
        bw[base + 1024] = bf16_rne(c - bf16_f(chv));
        bw[base + 2048] = shv;
        bw[base + 3072] = bf16_rne(ns - bf16_f(shv));
    }
    if (idx < 69632) {           // idft tables
        int m = idx / 1088, t = idx - m * 1088;
        int j = (m * t) & 2047;
        float s, c; sincosf(th * (float)j, &s, &c);
        int slab = m >> 4, kh = (m >> 3) & 1, e = m & 7;
        int base = BI_U + (slab * 8 + kh) * 8704 + t * 8 + e;
        unsigned short chv = bf16_rne(c), shv = bf16_rne(s);
        bw[base]         = chv;
        bw[base + 17408] = bf16_rne(c - bf16_f(chv));
        bw[base + 34816] = shv;
        bw[base + 52224] = bf16_rne(s - bf16_f(shv));
    }
}

// Forward (UNFOLDED) DFT via bf16-split MFMA. DATA: global_load_lds depth-3
// triple-buffer, CHUNK = 32 t (2 DMAs/chunk, 16 iterations). BASIS: direct
// global b128 reads in COMP. Block: 64m x 64ch x t-quarter; 4 waves.
// Grid (chtile8, b16, zz8) = 1024 blocks.
__global__ __launch_bounds__(256, 4) void fdft_kernel(const float* __restrict__ q,
                                                      const float* __restrict__ k,
                                                      float* __restrict__ ws) {
    const int chtile = blockIdx.x;        // 0..7 (64 ch)
    const int b      = blockIdx.y;
    const int zz     = blockIdx.z;        // tz*4 + part
    const int part   = zz & 3;
    const float* __restrict__ src = (zz >> 2) ? k : q;
    const unsigned short* __restrict__ basisF = (const unsigned short*)ws + BF_U;
    float* __restrict__ xp = ws + XP_F + (size_t)(zz * 16 + b) * 65536;

    // 3 data buffers x 2048 u32 (8 KB, 32 t x 64 ch); epilogue reuses first 16 KB
    __shared__ __align__(16) unsigned int lds32[6144];   // 24 KB

    const int tid  = threadIdx.x;
    const int lane = tid & 63;
    const int wv   = __builtin_amdgcn_readfirstlane(tid >> 6);
    const int wm   = wv >> 1, wc = wv & 1;   // m-half, ch-half
    const int ml   = lane & 31;
    const int khl  = lane >> 5;

    const int srow = tid >> 4;     // staging: t row 0..15 (and +16)
    const int sc4  = tid & 15;     // f4 index within 64 ch
    const float* __restrict__ ap = src + (size_t)b * 2048 * 512 + chtile * 64;

    f32x16 accR, accI;
#pragma unroll
    for (int i = 0; i < 16; ++i) { accR[i] = 0.f; accI[i] = 0.f; }

#define STAGE(BF, C)                                                          \
    {                                                                         \
        const int t0 = part * 512 + (C) * 32;                                 \
        gl_lds16(ap + (size_t)(t0 + srow) * 512 + sc4 * 4,                    \
                 lds32 + (BF) * 2048 + wv * 256);                             \
        gl_lds16(ap + (size_t)(t0 + 16 + srow) * 512 + sc4 * 4,               \
                 lds32 + (BF) * 2048 + 1024 + wv * 256);                      \
    }

#define COMPSUB(BF, C, SUB)                                                   \
    {                                                                         \
        const float* dl = (const float*)(lds32 + (BF) * 2048);                \
        float a[8];                                                           \
        _Pragma("unroll")                                                     \
        for (int e = 0; e < 8; ++e)                                           \
            a[e] = dl[((SUB) * 16 + khl * 8 + e) * 64 + wc * 32 + ml];        \
        short8v uH, uL;                                                       \
        _Pragma("unroll")                                                     \
        for (int e = 0; e < 8; ++e) {                                         \
            unsigned short hi = bf16_rne(a[e]);                               \
            uH[e] = (short)hi;                                                \
            uL[e] = (short)bf16_rne(a[e] - bf16_f(hi));                       \
        }                                                                     \
        const unsigned short* bb = basisF                                     \
            + (size_t)(part * 32 + (C) * 2 + (SUB)) * 4096                    \
            + khl * 512 + (wm * 32 + ml) * 8;                                 \
        short8v cH = *(const short8v*)(bb);                                   \
        short8v cL = *(const short8v*)(bb + 1024);                            \
        short8v sH = *(const short8v*)(bb + 2048);                            \
        short8v sL = *(const short8v*)(bb + 3072);                            \
        accR = __builtin_amdgcn_mfma_f32_32x32x16_bf16(cH, uH, accR, 0, 0, 0);\
        accR = __builtin_amdgcn_mfma_f32_32x32x16_bf16(cH, uL, accR, 0, 0, 0);\
        accR = __builtin_amdgcn_mfma_f32_32x32x16_bf16(cL, uH, accR, 0, 0, 0);\
        accI = __builtin_amdgcn_mfma_f32_32x32x16_bf16(sH, uH, accI, 0, 0, 0);\
        accI = __builtin_amdgcn_mfma_f32_32x32x16_bf16(sH, uL, accI, 0, 0, 0);\
        accI = __builtin_amdgcn_mfma_f32_32x32x16_bf16(sL, uH, accI, 0, 0, 0);\
    }
#define COMP(BF, C) COMPSUB(BF, C, 0) COMPSUB(BF, C, 1)

    // prologue: chunks 0..2 in flight (6 DMAs outstanding)
    STAGE(0, 0);
    STAGE(1, 1);
    STAGE(2, 2);
    for (int c = 0; c < 13; ++c) {         // stages chunks 3..15
        const int bf = c % 3;
        asm volatile("s_waitcnt vmcnt(4)" ::: "memory");   // chunk c landed
        __builtin_amdgcn_sched_barrier(0);
        __builtin_amdgcn_s_barrier();      // chunk c visible to all waves
        COMP(bf, c);
        __builtin_amdgcn_s_barrier();      // all waves done reading buf c
        __builtin_amdgcn_sched_barrier(0);
        STAGE(bf, c + 3);                  // refill freed buffer
    }
    // c = 13 (buffer 1): chunks 14,15 outstanding (4 DMAs)
    asm volatile("s_waitcnt vmcnt(4)" ::: "memory");
    __builtin_amdgcn_sched_barrier(0);
    __builtin_amdgcn_s_barrier();
    COMP(1, 13);
    __builtin_amdgcn_s_barrier();
    // c = 14 (buffer 2)
    asm volatile("s_waitcnt vmcnt(2)" ::: "memory");
    __builtin_amdgcn_sched_barrier(0);
    __builtin_amdgcn_s_barrier();
    COMP(2, 14);
    __builtin_amdgcn_s_barrier();
    // c = 15 (buffer 0)
    asm volatile("s_waitcnt vmcnt(0)" ::: "memory");
    __builtin_amdgcn_sched_barrier(0);
    __builtin_amdgcn_s_barrier();
    COMP(0, 15);
#undef STAGE
#undef COMPSUB
#undef COMP

    // epilogue: XOR-swizzled LDS transpose (64m x 64ch fp32 = 16 KB) -> [p][h][m][e]
    float* LF = (float*)lds32;
#pragma unroll 1
    for (int pass = 0; pass < 2; ++pass) {
        __syncthreads();
#pragma unroll
        for (int reg = 0; reg < 16; ++reg) {
            const int m = wm * 32 + (reg & 3) + 8 * (reg >> 2) + 4 * khl;
            const int chL = wc * 32 + ml;
            LF[m * 64 + (chL ^ ((m & 7) << 3))] = pass ? accI[reg] : accR[reg];
        }
        __syncthreads();
#pragma unroll
        for (int u8 = 0; u8 < 4; ++u8) {
            int unit = tid + u8 * 256;           // 1024 units = m64 x eh2 x h8
            int h = unit & 7, eh = (unit >> 3) & 1, m = unit >> 4;
            float4 val;
#pragma unroll
            for (int j = 0; j < 4; ++j) {
                int chL = (eh * 4 + j) * 8 + h;
                ((float*)&val)[j] = LF[m * 64 + (chL ^ ((m & 7) << 3))];
            }
            *(float4*)&xp[pass * 32768 + (h * 64 + m) * 64 + chtile * 8 + eh * 4] = val;
        }
    }
}

// Middle: per (b,h,x-half). 256 thr = 4 waves (wave -> 8 x-rows).
// S = Q K (complex), tanh, xqkv, scale -> YT (bf16 split, transposed)
__global__ __launch_bounds__(256) void mid_kernel(float* __restrict__ ws) {
    const int h = blockIdx.x, b = blockIdx.y, xh = blockIdx.z;
    unsigned short* __restrict__ YTb = (unsigned short*)ws + YT_U + (size_t)b * 131072;

    __shared__ float Qs[2][32][64];   // Q [xl][e]; reused as T [xl][y]
    __shared__ float Ksw[2][64][64];  // K [m][e] XOR-swizzled [m][e^m]

    const int tid = threadIdx.x;
    for (int slot = tid; slot < 1024; slot += 256) {   // p2 x 32m x 16f4
        int p = slot >> 9, ml = (slot >> 4) & 31, c4 = slot & 15;
        int off = ((p * 8 + h) * 64 + xh * 32 + ml) * 64 + c4 * 4;
        float4 acc = make_float4(0.f, 0.f, 0.f, 0.f);
#pragma unroll
        for (int part = 0; part < 4; ++part) {
            const float4 v = *(const float4*)(ws + XP_F + (size_t)(part * 16 + b) * 65536 + off);
            acc.x += v.x; acc.y += v.y; acc.z += v.z; acc.w += v.w;
        }
        *(float4*)(&Qs[p][ml][c4 * 4]) = acc;
    }
    for (int slot = tid; slot < 2048; slot += 256) {   // p2 x 64m x 16f4
        int p = slot >> 10, ml = (slot >> 4) & 63, c4 = slot & 15;
        int off = ((p * 8 + h) * 64 + ml) * 64 + c4 * 4;
        float4 acc = make_float4(0.f, 0.f, 0.f, 0.f);
#pragma unroll
        for (int part = 0; part < 4; ++part) {
            const float4 v = *(const float4*)(ws + XP_F + (size_t)((4 + part) * 16 + b) * 65536 + off);
            acc.x += v.x; acc.y += v.y; acc.z += v.z; acc.w += v.w;
        }
        Ksw[p][ml][(c4 * 4 + 0) ^ ml] = acc.x;
        Ksw[p][ml][(c4 * 4 + 1) ^ ml] = acc.y;
        Ksw[p][ml][(c4 * 4 + 2) ^ ml] = acc.z;
        Ksw[p][ml][(c4 * 4 + 3) ^ ml] = acc.w;
    }
    __syncthreads();

    const int lane = tid & 63;
    const int wid  = tid >> 6;   // 0..3
    const int xb   = wid * 8;

    float sr[8], si[8];
#pragma unroll
    for (int i = 0; i < 8; ++i) { sr[i] = 0.f; si[i] = 0.f; }
    const int y = lane;
    for (int e = 0; e < 64; ++e) {
        float kr = Ksw[0][y][e ^ y];
        float ki = Ksw[1][y][e ^ y];
#pragma unroll
        for (int i = 0; i < 8; ++i) {
            float qr = Qs[0][xb + i][e];
            float qi = Qs[1][xb + i][e];
            sr[i] += qr * kr; sr[i] -= qi * ki;
            si[i] += qr * ki; si[i] += qi * kr;
        }
    }
    float tr[8], ti[8];
#pragma unroll
    for (int i = 0; i < 8; ++i) { tr[i] = tanhf(sr[i]); ti[i] = tanhf(si[i]); }
    __syncthreads();
#pragma unroll
    for (int i = 0; i < 8; ++i) {
        Qs[0][xb + i][y] = tr[i];
        Qs[1][xb + i][y] = ti[i];
    }
    __syncthreads();

    float vr[8], vi[8];
#pragma unroll
    for (int i = 0; i < 8; ++i) { vr[i] = 0.f; vi[i] = 0.f; }
    const int e = lane;
    for (int yy = 0; yy < 64; ++yy) {
        float kr = Ksw[0][yy][e ^ yy];
        float ki = Ksw[1][yy][e ^ yy];
#pragma unroll
        for (int i = 0; i < 8; ++i) {
            float trr = Qs[0][xb + i][yy];
            float tii = Qs[1][xb + i][yy];
            vr[i] += trr * kr; vr[i] -= tii * ki;
            vi[i] += trr * ki; vi[i] += tii * kr;
        }
    }
#pragma unroll
    for (int i = 0; i < 8; ++i) {
        int x = xh * 32 + xb + i;
        float f = (x == 0 ? 1.0f : 2.0f) * (1.0f / (2048.0f * 4096.0f));
        float yr = f * vr[i];
        float yi = -f * vi[i];     // sign folded: out = P + Q with +sin table
        int off = (h * 64 + e) * 64 + x;
        unsigned short rH = bf16_rne(yr), iH = bf16_rne(yi);
        YTb[off]         = rH;
        YTb[32768 + off] = bf16_rne(yr - bf16_f(rH));
        YTb[65536 + off] = iH;
        YTb[98304 + off] = bf16_rne(yi - bf16_f(iH));
    }
}

// Inverse folded DFT via bf16-split MFMA. Block: 64t x 128ch; 4 waves (wt2 x wcc2),
// wave = 32t x 64ch (2 accs/side). Y staged in LDS from YT (m-slabs of 16, dbuf).
// P=sum cos*Yr, Q=sum sin*Yi; out[t]=P+Q (t<=1024), out[2048-t]=P-Q (1<=t<=1023).
__global__ __launch_bounds__(256, 3) void idft_kernel(const float* __restrict__ ws,
                                                      float* __restrict__ out) {
    const int tt0    = blockIdx.x * 64;   // 0..1024
    const int chtile = blockIdx.y;        // 0..3
    const int b      = blockIdx.z;
    const unsigned short* __restrict__ basisI = (const unsigned short*)ws + BI_U;
    const unsigned short* __restrict__ YTb = (const unsigned short*)ws + YT_U + (size_t)b * 131072;

    // [tbl4][ch128][24] per buffer = 12288 ushorts (stride 24 for alignment + banks)
    __shared__ __align__(16) unsigned short ldsY[2][12288];   // 48 KB

    const int tid  = threadIdx.x;
    const int lane = tid & 63;
    const int wv   = tid >> 6;
    const int wt   = wv >> 1, wcc = wv & 1;
    const int ml   = lane & 31;
    const int khl  = lane >> 5;

    f32x16 accP0, accP1, accQ0, accQ1;
#pragma unroll
    for (int i = 0; i < 16; ++i) { accP0[i] = 0.f; accP1[i] = 0.f; accQ0[i] = 0.f; accQ1[i] = 0.f; }

    const int tblA = tid >> 7;            // staging row A: tables 0,1
    const int chlA = tid & 127;
    short8v sA0, sA1, sB0, sB1;

    auto LOAD = [&](int s) {
        const unsigned short* gA = YTb + tblA * 32768 + (chtile * 128 + chlA) * 64 + s * 16;
        const unsigned short* gB = gA + 2 * 32768;      // tables 2,3
        sA0 = *(const short8v*)(gA);
        sA1 = *(const short8v*)(gA + 8);
        sB0 = *(const short8v*)(gB);
        sB1 = *(const short8v*)(gB + 8);
    };
    auto WRITE = [&](int bf) {
        unsigned short* D = &ldsY[bf][0];
        const int offA = tblA * 3072 + chlA * 24;
        *(short8v*)(D + offA)            = sA0;
        *(short8v*)(D + offA + 8)        = sA1;
        *(short8v*)(D + offA + 2 * 3072)     = sB0;
        *(short8v*)(D + offA + 2 * 3072 + 8) = sB1;
    };
    auto COMP = [&](int bf, int s) {
        const unsigned short* bb = basisI + (s * 8 + khl) * 8704 + (tt0 + wt * 32 + ml) * 8;
        short8v cH = *(const short8v*)(bb);
        short8v cL = *(const short8v*)(bb + 17408);
        short8v sH = *(const short8v*)(bb + 34816);
        short8v sL = *(const short8v*)(bb + 52224);
        const unsigned short* L = &ldsY[bf][0];
        const int b0 = (wcc * 64 + ml) * 24 + khl * 8;
        short8v yrH0 = *(const short8v*)(L + b0);
        short8v yrL0 = *(const short8v*)(L + 3072 + b0);
        short8v yiH0 = *(const short8v*)(L + 6144 + b0);
        short8v yiL0 = *(const short8v*)(L + 9216 + b0);
        const int b1 = b0 + 32 * 24;
        short8v yrH1 = *(const short8v*)(L + b1);
        short8v yrL1 = *(const short8v*)(L + 3072 + b1);
        short8v yiH1 = *(const short8v*)(L + 6144 + b1);
        short8v yiL1 = *(const short8v*)(L + 9216 + b1);
        accP0 = __builtin_amdgcn_mfma_f32_32x32x16_bf16(cH, yrH0, accP0, 0, 0, 0);
        accP0 = __builtin_amdgcn_mfma_f32_32x32x16_bf16(cH, yrL0, accP0, 0, 0, 0);
        accP0 = __builtin_amdgcn_mfma_f32_32x32x16_bf16(cL, yrH0, accP0, 0, 0, 0);
        accQ0 = __builtin_amdgcn_mfma_f32_32x32x16_bf16(sH, yiH0, accQ0, 0, 0, 0);
        accQ0 = __builtin_amdgcn_mfma_f32_32x32x16_bf16(sH, yiL0, accQ0, 0, 0, 0);
        accQ0 = __builtin_amdgcn_mfma_f32_32x32x16_bf16(sL, yiH0, accQ0, 0, 0, 0);
        accP1 = __builtin_amdgcn_mfma_f32_32x32x16_bf16(cH, yrH1, accP1, 0, 0, 0);
        accP1 = __builtin_amdgcn_mfma_f32_32x32x16_bf16(cH, yrL1, accP1, 0, 0, 0);
        accP1 = __builtin_amdgcn_mfma_f32_32x32x16_bf16(cL, yrH1, accP1, 0, 0, 0);
        accQ1 = __builtin_amdgcn_mfma_f32_32x32x16_bf16(sH, yiH1, accQ1, 0, 0, 0);
        accQ1 = __builtin_amdgcn_mfma_f32_32x32x16_bf16(sH, yiL1, accQ1, 0, 0, 0);
        accQ1 = __builtin_amdgcn_mfma_f32_32x32x16_bf16(sL, yiH1, accQ1, 0, 0, 0);
    };

    LOAD(0); WRITE(0); __syncthreads();
    for (int s = 0; s < 4; ++s) {
        if (s < 3) LOAD(s + 1);
        COMP(s & 1, s);
        if (s < 3) { WRITE((s + 1) & 1); __syncthreads(); }
    }

    float* __restrict__ ob = out + (size_t)b * 2048 * 512;
#pragma unroll
    for (int reg = 0; reg < 16; ++reg) {
        const int tL = wt * 32 + (reg & 3) + 8 * (reg >> 2) + 4 * khl;
        const int t  = tt0 + tL;
        const int ch0 = chtile * 128 + wcc * 64 + ml;
        float p0 = accP0[reg], q0 = accQ0[reg];
        float p1 = accP1[reg], q1 = accQ1[reg];
        if (t <= 1024) {
            ob[(size_t)t * 512 + ch0]      = p0 + q0;
            ob[(size_t)t * 512 + ch0 + 32] = p1 + q1;
        }
        if (t >= 1 && t <= 1023) {
            ob[(size_t)(2048 - t) * 512 + ch0]      = p0 - q0;
            ob[(size_t)(2048 - t) * 512 + ch0 + 32] = p1 - q1;
        }
    }
}

extern "C" void kernel_launch(void* const* d_in, const int* in_sizes, int n_in,
                              void* d_out, int out_size, void* d_ws, size_t ws_size,
                              hipStream_t stream) {
    const float* q = (const float*)d_in[0];
    const float* k = (const float*)d_in[1];
    float* ws = (float*)d_ws;      // ~39.4 MB used
    float* out = (float*)d_out;

    hipLaunchKernelGGL(basis_kernel, dim3(512), dim3(256), 0, stream, ws);
    hipLaunchKernelGGL(fdft_kernel, dim3(8, 16, 8), dim3(256), 0, stream, q, k, ws);
    hipLaunchKernelGGL(mid_kernel, dim3(8, 16, 2), dim3(256), 0, stream, ws);
    hipLaunchKernelGGL(idft_kernel, dim3(17, 4, 16), dim3(256), 0, stream, ws, out);
}

// Round 21
// 95.251 us; speedup vs baseline: 1.2467x; 1.0712x over previous
//
#include <hip/hip_runtime.h>
#include <math.h>

typedef __attribute__((ext_vector_type(8))) short short8v;   // 8 bf16
typedef __attribute__((ext_vector_type(16))) float f32x16;   // MFMA acc

// ws layout:
//  ushort offsets:
//   basisF (fdft) [cc64][tbl4][kh2][m64][e8]     @ u 0        (262144 u)
//     tbl: 0=cosHi 1=cosLo 2=(-sin)Hi 3=(-sin)Lo ; t = cc*16 + kh*8 + e  (folded, t<1024)
//   basisI (idft) [slab4][tbl4][kh2][t1088][e8]  @ u 262144   (278528 u)
//     tbl: 0=cosHi 1=cosLo 2=sinHi 3=sinLo ; m = slab*16 + kh*8 + e
//  float offsets:
//   XP [zz8 = tz*4+part][b16][p2][h8][m64][e64]  @ f 270336   (8388608 f)
//  ushort offsets:
//   YT [b16][tbl4][ch512][m64]                   @ u 17317888 (2097152 u)
//     tbl: 0=YrHi 1=YrLo 2=YiHi 3=YiLo (Yi sign-folded)
#define BF_U 0
#define BI_U 262144
#define XP_F 270336
#define YT_U 17317888

__device__ inline unsigned short bf16_rne(float x) {
    unsigned int u = __float_as_uint(x);
    u += 0x7FFFu + ((u >> 16) & 1u);
    return (unsigned short)(u >> 16);
}
__device__ inline float bf16_f(unsigned short h) {
    return __uint_as_float(((unsigned int)h) << 16);
}

__global__ __launch_bounds__(256) void basis_kernel(float* __restrict__ w) {
    int idx = blockIdx.x * 256 + threadIdx.x;
    const float th = 0.0030679615757712823f; // 2*pi/2048
    unsigned short* bw = (unsigned short*)w;
    if (idx < 65536) {           // fdft tables (folded, t<1024)
        int t = idx >> 6, m = idx & 63;
        int j = (m * t) & 2047;
        float s, c; sincosf(th * (float)j, &s, &c);
        float ns = -s;
        int cc = t >> 4, kh = (t >> 3) & 1, e = t & 7;
        int base = BF_U + cc * 4096 + kh * 512 + m * 8 + e;
        unsigned short chv = bf16_rne(c), shv = bf16_rne(ns);
        bw[base]        = chv;
        bw[base + 1024] = bf16_rne(c - bf16_f(chv));
        bw[base + 2048] = shv;
        bw[base + 3072] = bf16_rne(ns - bf16_f(shv));
    }
    if (idx < 69632) {           // idft tables
        int m = idx / 1088, t = idx - m * 1088;
        int j = (m * t) & 2047;
        float s, c; sincosf(th * (float)j, &s, &c);
        int slab = m >> 4, kh = (m >> 3) & 1, e = m & 7;
        int base = BI_U + (slab * 8 + kh) * 8704 + t * 8 + e;
        unsigned short chv = bf16_rne(c), shv = bf16_rne(s);
        bw[base]         = chv;
        bw[base + 17408] = bf16_rne(c - bf16_f(chv));
        bw[base + 34816] = shv;
        bw[base + 52224] = bf16_rne(s - bf16_f(shv));
    }
}

// Forward folded DFT via bf16-split MFMA (round-9 verified fastest variant).
// Block: 32m x 128ch x one t-quarter; 4 waves (ch quadrants). Reg-staged LDS
// dbuf (T14 style); basis A-frags direct from global (L2-hot).
// Grid (chtile4, b16, zz8*mgrp2) = 1024 blocks.
__global__ __launch_bounds__(256, 4) void fdft_kernel(const float* __restrict__ q,
                                                      const float* __restrict__ k,
                                                      float* __restrict__ ws) {
    const int chtile = blockIdx.x;
    const int b      = blockIdx.y;
    const int zz     = blockIdx.z >> 1;   // tz*4 + part
    const int mgrp   = blockIdx.z & 1;
    const int part   = zz & 3;
    const float* __restrict__ src = (zz >> 2) ? k : q;
    const unsigned short* __restrict__ basisF = (const unsigned short*)ws + BF_U;
    float* __restrict__ xp = ws + XP_F + (size_t)(zz * 16 + b) * 65536;

    // data only: [tbl4(uH,uL,vH,vL)][kh2][ch128][e8] per buffer = 8192 ushorts
    __shared__ __align__(16) unsigned short lds[2][8192];   // 32 KB

    const int tid  = threadIdx.x;
    const int lane = tid & 63;
    const int wc   = tid >> 6;      // ch quadrant 0..3
    const int ml   = lane & 31;
    const int khl  = lane >> 5;

    const int chl = tid & 127;      // staging: thread -> (ch, kh)
    const int kh  = tid >> 7;
    const float* __restrict__ ap = src + (size_t)b * 2048 * 512 + chtile * 128 + chl;

    f32x16 accR, accI;
#pragma unroll
    for (int i = 0; i < 16; ++i) { accR[i] = 0.f; accI[i] = 0.f; }

    float av[8], pv[8];

    auto LOAD = [&](int s) {
        const int t0 = part * 256 + s * 16 + kh * 8;
#pragma unroll
        for (int e = 0; e < 8; ++e) {
            int t = t0 + e;
            int pr = (t == 0) ? 1024 : 2048 - t;
            av[e] = ap[(size_t)t * 512];
            pv[e] = ap[(size_t)pr * 512];
        }
    };
    auto WRITE = [&](int bf) {
        unsigned short* D = &lds[bf][0];
        short8v xu, xl, xv, xw;
#pragma unroll
        for (int e = 0; e < 8; ++e) {
            float u = av[e] + pv[e], v = av[e] - pv[e];
            unsigned short uh = bf16_rne(u); unsigned short vh = bf16_rne(v);
            xu[e] = (short)uh; xl[e] = (short)bf16_rne(u - bf16_f(uh));
            xv[e] = (short)vh; xw[e] = (short)bf16_rne(v - bf16_f(vh));
        }
        const int doff = kh * 1024 + chl * 8;
        *(short8v*)(D + doff)        = xu;
        *(short8v*)(D + doff + 2048) = xl;
        *(short8v*)(D + doff + 4096) = xv;
        *(short8v*)(D + doff + 6144) = xw;
    };
    auto COMP = [&](int bf, int s) {
        const unsigned short* bb = basisF + (part * 16 + s) * 4096
                                 + khl * 512 + (mgrp * 32 + ml) * 8;
        short8v cH = *(const short8v*)(bb);
        short8v cL = *(const short8v*)(bb + 1024);
        short8v sH = *(const short8v*)(bb + 2048);
        short8v sL = *(const short8v*)(bb + 3072);
        const unsigned short* L = &lds[bf][0];
        const int b0 = khl * 1024 + (wc * 32 + ml) * 8;
        short8v uH = *(const short8v*)(L + b0);
        short8v uL = *(const short8v*)(L + b0 + 2048);
        short8v vH = *(const short8v*)(L + b0 + 4096);
        short8v vL = *(const short8v*)(L + b0 + 6144);
        accR = __builtin_amdgcn_mfma_f32_32x32x16_bf16(cH, uH, accR, 0, 0, 0);
        accR = __builtin_amdgcn_mfma_f32_32x32x16_bf16(cH, uL, accR, 0, 0, 0);
        accR = __builtin_amdgcn_mfma_f32_32x32x16_bf16(cL, uH, accR, 0, 0, 0);
        accI = __builtin_amdgcn_mfma_f32_32x32x16_bf16(sH, vH, accI, 0, 0, 0);
        accI = __builtin_amdgcn_mfma_f32_32x32x16_bf16(sH, vL, accI, 0, 0, 0);
        accI = __builtin_amdgcn_mfma_f32_32x32x16_bf16(sL, vH, accI, 0, 0, 0);
    };

    LOAD(0); WRITE(0); __syncthreads();
    for (int s = 0; s < 16; ++s) {
        if (s < 15) LOAD(s + 1);
        COMP(s & 1, s);
        if (s < 15) { WRITE((s + 1) & 1); __syncthreads(); }
    }

    if (part == 0) {   // odd-m correction: u[0] folded a1024 with +1 for all m
        float a0 = src[(size_t)b * 2048 * 512 + (size_t)1024 * 512
                       + chtile * 128 + wc * 32 + ml];
#pragma unroll
        for (int reg = 1; reg < 16; reg += 2) accR[reg] -= 2.f * a0;
    }

    // epilogue: LDS transpose (32m rows, stride 129) -> [p][h][m][e] stores
    float* LF = (float*)(&lds[0][0]);   // 32*129*4 = 16.5 KB
#pragma unroll 1
    for (int pass = 0; pass < 2; ++pass) {
        __syncthreads();
#pragma unroll
        for (int reg = 0; reg < 16; ++reg) {
            const int mL = (reg & 3) + 8 * (reg >> 2) + 4 * khl;
            LF[mL * 129 + wc * 32 + ml] = pass ? accI[reg] : accR[reg];
        }
        __syncthreads();
#pragma unroll
        for (int u8 = 0; u8 < 4; ++u8) {
            int unit = tid + u8 * 256;              // 1024 units = 32m x 32 f4
            int e4 = unit & 3, h = (unit >> 2) & 7, mL = unit >> 5;
            float4 val;
            val.x = LF[mL * 129 + ((e4 * 4 + 0) * 8 + h)];
            val.y = LF[mL * 129 + ((e4 * 4 + 1) * 8 + h)];
            val.z = LF[mL * 129 + ((e4 * 4 + 2) * 8 + h)];
            val.w = LF[mL * 129 + ((e4 * 4 + 3) * 8 + h)];
            *(float4*)&xp[pass * 32768 + (h * 64 + mgrp * 32 + mL) * 64
                          + chtile * 16 + e4 * 4] = val;
        }
    }
}

// Middle: per (b,h,x-half). 256 thr = 4 waves (wave -> 8 x-rows).
// S = Q K (complex), tanh, xqkv, scale -> YT (bf16 split, transposed)
__global__ __launch_bounds__(256) void mid_kernel(float* __restrict__ ws) {
    const int h = blockIdx.x, b = blockIdx.y, xh = blockIdx.z;
    unsigned short* __restrict__ YTb = (unsigned short*)ws + YT_U + (size_t)b * 131072;

    __shared__ float Qs[2][32][64];   // Q [xl][e]; reused as T [xl][y]
    __shared__ float Ksw[2][64][64];  // K [m][e] XOR-swizzled [m][e^m]

    const int tid = threadIdx.x;
    for (int slot = tid; slot < 1024; slot += 256) {   // p2 x 32m x 16f4
        int p = slot >> 9, ml = (slot >> 4) & 31, c4 = slot & 15;
        int off = ((p * 8 + h) * 64 + xh * 32 + ml) * 64 + c4 * 4;
        float4 acc = make_float4(0.f, 0.f, 0.f, 0.f);
#pragma unroll
        for (int part = 0; part < 4; ++part) {
            const float4 v = *(const float4*)(ws + XP_F + (size_t)(part * 16 + b) * 65536 + off);
            acc.x += v.x; acc.y += v.y; acc.z += v.z; acc.w += v.w;
        }
        *(float4*)(&Qs[p][ml][c4 * 4]) = acc;
    }
    for (int slot = tid; slot < 2048; slot += 256) {   // p2 x 64m x 16f4
        int p = slot >> 10, ml = (slot >> 4) & 63, c4 = slot & 15;
        int off = ((p * 8 + h) * 64 + ml) * 64 + c4 * 4;
        float4 acc = make_float4(0.f, 0.f, 0.f, 0.f);
#pragma unroll
        for (int part = 0; part < 4; ++part) {
            const float4 v = *(const float4*)(ws + XP_F + (size_t)((4 + part) * 16 + b) * 65536 + off);
            acc.x += v.x; acc.y += v.y; acc.z += v.z; acc.w += v.w;
        }
        Ksw[p][ml][(c4 * 4 + 0) ^ ml] = acc.x;
        Ksw[p][ml][(c4 * 4 + 1) ^ ml] = acc.y;
        Ksw[p][ml][(c4 * 4 + 2) ^ ml] = acc.z;
        Ksw[p][ml][(c4 * 4 + 3) ^ ml] = acc.w;
    }
    __syncthreads();

    const int lane = tid & 63;
    const int wid  = tid >> 6;   // 0..3
    const int xb   = wid * 8;

    float sr[8], si[8];
#pragma unroll
    for (int i = 0; i < 8; ++i) { sr[i] = 0.f; si[i] = 0.f; }
    const int y = lane;
    for (int e = 0; e < 64; ++e) {
        float kr = Ksw[0][y][e ^ y];
        float ki = Ksw[1][y][e ^ y];
#pragma unroll
        for (int i = 0; i < 8; ++i) {
            float qr = Qs[0][xb + i][e];
            float qi = Qs[1][xb + i][e];
            sr[i] += qr * kr; sr[i] -= qi * ki;
            si[i] += qr * ki; si[i] += qi * kr;
        }
    }
    float tr[8], ti[8];
#pragma unroll
    for (int i = 0; i < 8; ++i) { tr[i] = tanhf(sr[i]); ti[i] = tanhf(si[i]); }
    __syncthreads();
#pragma unroll
    for (int i = 0; i < 8; ++i) {
        Qs[0][xb + i][y] = tr[i];
        Qs[1][xb + i][y] = ti[i];
    }
    __syncthreads();

    float vr[8], vi[8];
#pragma unroll
    for (int i = 0; i < 8; ++i) { vr[i] = 0.f; vi[i] = 0.f; }
    const int e = lane;
    for (int yy = 0; yy < 64; ++yy) {
        float kr = Ksw[0][yy][e ^ yy];
        float ki = Ksw[1][yy][e ^ yy];
#pragma unroll
        for (int i = 0; i < 8; ++i) {
            float trr = Qs[0][xb + i][yy];
            float tii = Qs[1][xb + i][yy];
            vr[i] += trr * kr; vr[i] -= tii * ki;
            vi[i] += trr * ki; vi[i] += tii * kr;
        }
    }
#pragma unroll
    for (int i = 0; i < 8; ++i) {
        int x = xh * 32 + xb + i;
        float f = (x == 0 ? 1.0f : 2.0f) * (1.0f / (2048.0f * 4096.0f));
        float yr = f * vr[i];
        float yi = -f * vi[i];     // sign folded: out = P + Q with +sin table
        int off = (h * 64 + e) * 64 + x;
        unsigned short rH = bf16_rne(yr), iH = bf16_rne(yi);
        YTb[off]         = rH;
        YTb[32768 + off] = bf16_rne(yr - bf16_f(rH));
        YTb[65536 + off] = iH;
        YTb[98304 + off] = bf16_rne(yi - bf16_f(iH));
    }
}

// Inverse folded DFT via bf16-split MFMA. Block: 64t x 128ch; 4 waves (wt2 x wcc2),
// wave = 32t x 64ch (2 accs/side). Y staged in LDS from YT (m-slabs of 16, dbuf).
// P=sum cos*Yr, Q=sum sin*Yi; out[t]=P+Q (t<=1024), out[2048-t]=P-Q (1<=t<=1023).
__global__ __launch_bounds__(256, 3) void idft_kernel(const float* __restrict__ ws,
                                                      float* __restrict__ out) {
    const int tt0    = blockIdx.x * 64;   // 0..1024
    const int chtile = blockIdx.y;        // 0..3
    const int b      = blockIdx.z;
    const unsigned short* __restrict__ basisI = (const unsigned short*)ws + BI_U;
    const unsigned short* __restrict__ YTb = (const unsigned short*)ws + YT_U + (size_t)b * 131072;

    // [tbl4][ch128][24] per buffer = 12288 ushorts (stride 24 for alignment + banks)
    __shared__ __align__(16) unsigned short ldsY[2][12288];   // 48 KB

    const int tid  = threadIdx.x;
    const int lane = tid & 63;
    const int wv   = tid >> 6;
    const int wt   = wv >> 1, wcc = wv & 1;
    const int ml   = lane & 31;
    const int khl  = lane >> 5;

    f32x16 accP0, accP1, accQ0, accQ1;
#pragma unroll
    for (int i = 0; i < 16; ++i) { accP0[i] = 0.f; accP1[i] = 0.f; accQ0[i] = 0.f; accQ1[i] = 0.f; }

    const int tblA = tid >> 7;            // staging row A: tables 0,1
    const int chlA = tid & 127;
    short8v sA0, sA1, sB0, sB1;

    auto LOAD = [&](int s) {
        const unsigned short* gA = YTb + tblA * 32768 + (chtile * 128 + chlA) * 64 + s * 16;
        const unsigned short* gB = gA + 2 * 32768;      // tables 2,3
        sA0 = *(const short8v*)(gA);
        sA1 = *(const short8v*)(gA + 8);
        sB0 = *(const short8v*)(gB);
        sB1 = *(const short8v*)(gB + 8);
    };
    auto WRITE = [&](int bf) {
        unsigned short* D = &ldsY[bf][0];
        const int offA = tblA * 3072 + chlA * 24;
        *(short8v*)(D + offA)            = sA0;
        *(short8v*)(D + offA + 8)        = sA1;
        *(short8v*)(D + offA + 2 * 3072)     = sB0;
        *(short8v*)(D + offA + 2 * 3072 + 8) = sB1;
    };
    auto COMP = [&](int bf, int s) {
        const unsigned short* bb = basisI + (s * 8 + khl) * 8704 + (tt0 + wt * 32 + ml) * 8;
        short8v cH = *(const short8v*)(bb);
        short8v cL = *(const short8v*)(bb + 17408);
        short8v sH = *(const short8v*)(bb + 34816);
        short8v sL = *(const short8v*)(bb + 52224);
        const unsigned short* L = &ldsY[bf][0];
        const int b0 = (wcc * 64 + ml) * 24 + khl * 8;
        short8v yrH0 = *(const short8v*)(L + b0);
        short8v yrL0 = *(const short8v*)(L + 3072 + b0);
        short8v yiH0 = *(const short8v*)(L + 6144 + b0);
        short8v yiL0 = *(const short8v*)(L + 9216 + b0);
        const int b1 = b0 + 32 * 24;
        short8v yrH1 = *(const short8v*)(L + b1);
        short8v yrL1 = *(const short8v*)(L + 3072 + b1);
        short8v yiH1 = *(const short8v*)(L + 6144 + b1);
        short8v yiL1 = *(const short8v*)(L + 9216 + b1);
        accP0 = __builtin_amdgcn_mfma_f32_32x32x16_bf16(cH, yrH0, accP0, 0, 0, 0);
        accP0 = __builtin_amdgcn_mfma_f32_32x32x16_bf16(cH, yrL0, accP0, 0, 0, 0);
        accP0 = __builtin_amdgcn_mfma_f32_32x32x16_bf16(cL, yrH0, accP0, 0, 0, 0);
        accQ0 = __builtin_amdgcn_mfma_f32_32x32x16_bf16(sH, yiH0, accQ0, 0, 0, 0);
        accQ0 = __builtin_amdgcn_mfma_f32_32x32x16_bf16(sH, yiL0, accQ0, 0, 0, 0);
        accQ0 = __builtin_amdgcn_mfma_f32_32x32x16_bf16(sL, yiH0, accQ0, 0, 0, 0);
        accP1 = __builtin_amdgcn_mfma_f32_32x32x16_bf16(cH, yrH1, accP1, 0, 0, 0);
        accP1 = __builtin_amdgcn_mfma_f32_32x32x16_bf16(cH, yrL1, accP1, 0, 0, 0);
        accP1 = __builtin_amdgcn_mfma_f32_32x32x16_bf16(cL, yrH1, accP1, 0, 0, 0);
        accQ1 = __builtin_amdgcn_mfma_f32_32x32x16_bf16(sH, yiH1, accQ1, 0, 0, 0);
        accQ1 = __builtin_amdgcn_mfma_f32_32x32x16_bf16(sH, yiL1, accQ1, 0, 0, 0);
        accQ1 = __builtin_amdgcn_mfma_f32_32x32x16_bf16(sL, yiH1, accQ1, 0, 0, 0);
    };

    LOAD(0); WRITE(0); __syncthreads();
    for (int s = 0; s < 4; ++s) {
        if (s < 3) LOAD(s + 1);
        COMP(s & 1, s);
        if (s < 3) { WRITE((s + 1) & 1); __syncthreads(); }
    }

    float* __restrict__ ob = out + (size_t)b * 2048 * 512;
#pragma unroll
    for (int reg = 0; reg < 16; ++reg) {
        const int tL = wt * 32 + (reg & 3) + 8 * (reg >> 2) + 4 * khl;
        const int t  = tt0 + tL;
        const int ch0 = chtile * 128 + wcc * 64 + ml;
        float p0 = accP0[reg], q0 = accQ0[reg];
        float p1 = accP1[reg], q1 = accQ1[reg];
        if (t <= 1024) {
            ob[(size_t)t * 512 + ch0]      = p0 + q0;
            ob[(size_t)t * 512 + ch0 + 32] = p1 + q1;
        }
        if (t >= 1 && t <= 1023) {
            ob[(size_t)(2048 - t) * 512 + ch0]      = p0 - q0;
            ob[(size_t)(2048 - t) * 512 + ch0 + 32] = p1 - q1;
        }
    }
}

extern "C" void kernel_launch(void* const* d_in, const int* in_sizes, int n_in,
                              void* d_out, int out_size, void* d_ws, size_t ws_size,
                              hipStream_t stream) {
    const float* q = (const float*)d_in[0];
    const float* k = (const float*)d_in[1];
    float* ws = (float*)d_ws;      // ~38.8 MB used
    float* out = (float*)d_out;

    hipLaunchKernelGGL(basis_kernel, dim3(272), dim3(256), 0, stream, ws);
    hipLaunchKernelGGL(fdft_kernel, dim3(4, 16, 16), dim3(256), 0, stream, q, k, ws);
    hipLaunchKernelGGL(mid_kernel, dim3(8, 16, 2), dim3(256), 0, stream, ws);
    hipLaunchKernelGGL(idft_kernel, dim3(17, 4, 16), dim3(256), 0, stream, ws, out);
}

// Round 22
// 87.617 us; speedup vs baseline: 1.3553x; 1.0871x over previous
//
#include <hip/hip_runtime.h>
#include <math.h>

typedef __attribute__((ext_vector_type(8))) short short8v;   // 8 bf16
typedef __attribute__((ext_vector_type(16))) float f32x16;   // MFMA acc

// ws layout:
//  ushort offsets:
//   basisF (fdft) [cc64][tbl4][kh2][m64][e8]     @ u 0        (262144 u)
//     tbl: 0=cosHi 1=cosLo 2=(-sin)Hi 3=(-sin)Lo ; t = cc*16 + kh*8 + e  (folded, t<1024)
//   basisI (idft) [slab4][tbl4][kh2][t1088][e8]  @ u 262144   (278528 u)
//     tbl: 0=cosHi 1=cosLo 2=sinHi 3=sinLo ; m = slab*16 + kh*8 + e
//  float offsets:
//   XP [zz8 = tz*4+part][b16][p2][h8][m64][e64]  @ f 270336   (8388608 f)
//  ushort offsets:
//   YT [b16][tbl4][ch512][m64]                   @ u 17317888 (2097152 u)
//     tbl: 0=YrHi 1=YrLo 2=YiHi 3=YiLo (Yi sign-folded)
#define BF_U 0
#define BI_U 262144
#define XP_F 270336
#define YT_U 17317888

__device__ inline unsigned short bf16_rne(float x) {
    unsigned int u = __float_as_uint(x);
    u += 0x7FFFu + ((u >> 16) & 1u);
    return (unsigned short)(u >> 16);
}
__device__ inline float bf16_f(unsigned short h) {
    return __uint_as_float(((unsigned int)h) << 16);
}

__global__ __launch_bounds__(256) void basis_kernel(float* __restrict__ w) {
    int idx = blockIdx.x * 256 + threadIdx.x;
    const float th = 0.0030679615757712823f; // 2*pi/2048
    unsigned short* bw = (unsigned short*)w;
    if (idx < 65536) {           // fdft tables (folded, t<1024)
        int t = idx >> 6, m = idx & 63;
        int j = (m * t) & 2047;
        float s, c; sincosf(th * (float)j, &s, &c);
        float ns = -s;
        int cc = t >> 4, kh = (t >> 3) & 1, e = t & 7;
        int base = BF_U + cc * 4096 + kh * 512 + m * 8 + e;
        unsigned short chv = bf16_rne(c), shv = bf16_rne(ns);
        bw[base]        = chv;
        bw[base + 1024] = bf16_rne(c - bf16_f(chv));
        bw[base + 2048] = shv;
        bw[base + 3072] = bf16_rne(ns - bf16_f(shv));
    }
    if (idx < 69632) {           // idft tables
        int m = idx / 1088, t = idx - m * 1088;
        int j = (m * t) & 2047;
        float s, c; sincosf(th * (float)j, &s, &c);
        int slab = m >> 4, kh = (m >> 3) & 1, e = m & 7;
        int base = BI_U + (slab * 8 + kh) * 8704 + t * 8 + e;
        unsigned short chv = bf16_rne(c), shv = bf16_rne(s);
        bw[base]         = chv;
        bw[base + 17408] = bf16_rne(c - bf16_f(chv));
        bw[base + 34816] = shv;
        bw[base + 52224] = bf16_rne(s - bf16_f(shv));
    }
}

// Forward folded DFT via bf16-split MFMA (round-7 structure — fastest measured).
// Block: 64m x 128ch x one t-quarter; 4 waves (wm2 x wc2), wave = 32m x 64ch.
// Reg-staged LDS dbuf; basis staged through LDS. Grid (chtile4, b16, z8) = 512.
__global__ __launch_bounds__(256, 2) void fdft_kernel(const float* __restrict__ q,
                                                      const float* __restrict__ k,
                                                      float* __restrict__ ws) {
    const int chtile = blockIdx.x;       // 0..3 (128 ch)
    const int b      = blockIdx.y;
    const int z      = blockIdx.z;       // tz*4 + part
    const int part   = z & 3;
    const float* __restrict__ src = (z >> 2) ? k : q;
    const unsigned short* __restrict__ basisF = (const unsigned short*)ws + BF_U;
    float* __restrict__ xp = ws + XP_F + (size_t)(z * 16 + b) * 65536;

    // per chunk (ushorts): basis 4096 ([tbl][kh][m][e]) + data 8192 ([tbl][kh][ch][e])
    __shared__ __align__(16) unsigned short lds[2][12288];   // 48 KB

    const int tid  = threadIdx.x;
    const int lane = tid & 63;
    const int wv   = tid >> 6;
    const int wm   = wv >> 1, wc = wv & 1;
    const int ml   = lane & 31;
    const int khl  = lane >> 5;

    const int chl = tid & 127;     // staging: thread -> (ch, kh)
    const int kh  = tid >> 7;
    const float* __restrict__ ap = src + (size_t)b * 2048 * 512 + chtile * 128 + chl;

    f32x16 accR0, accR1, accI0, accI1;
#pragma unroll
    for (int i = 0; i < 16; ++i) { accR0[i] = 0.f; accR1[i] = 0.f; accI0[i] = 0.f; accI1[i] = 0.f; }

    float av[8], pv[8];
    short8v bas0, bas1;

    auto LOAD = [&](int s) {
        const int t0 = part * 256 + s * 16 + kh * 8;
#pragma unroll
        for (int e = 0; e < 8; ++e) {
            int t = t0 + e;
            int pr = (t == 0) ? 1024 : 2048 - t;
            av[e] = ap[(size_t)t * 512];
            pv[e] = ap[(size_t)pr * 512];
        }
        const unsigned short* bsrc = basisF + (size_t)(part * 16 + s) * 4096;
        bas0 = *(const short8v*)(bsrc + tid * 8);
        bas1 = *(const short8v*)(bsrc + 2048 + tid * 8);
    };
    auto WRITE = [&](int bf) {
        unsigned short* D = &lds[bf][0];
        *(short8v*)(D + tid * 8)        = bas0;
        *(short8v*)(D + 2048 + tid * 8) = bas1;
        short8v xu, xl, xv, xw;
#pragma unroll
        for (int e = 0; e < 8; ++e) {
            float u = av[e] + pv[e], v = av[e] - pv[e];
            unsigned short uh = bf16_rne(u); unsigned short vh = bf16_rne(v);
            xu[e] = (short)uh; xl[e] = (short)bf16_rne(u - bf16_f(uh));
            xv[e] = (short)vh; xw[e] = (short)bf16_rne(v - bf16_f(vh));
        }
        const int doff = 4096 + (kh * 128 + chl) * 8;
        *(short8v*)(D + doff)        = xu;
        *(short8v*)(D + doff + 2048) = xl;
        *(short8v*)(D + doff + 4096) = xv;
        *(short8v*)(D + doff + 6144) = xw;
    };
    auto COMP = [&](int bf) {
        const unsigned short* L = &lds[bf][0];
        const int aoff = (khl * 64 + wm * 32 + ml) * 8;
        short8v cH = *(const short8v*)(L + aoff);
        short8v cL = *(const short8v*)(L + 1024 + aoff);
        short8v sH = *(const short8v*)(L + 2048 + aoff);
        short8v sL = *(const short8v*)(L + 3072 + aoff);
        const int b0 = 4096 + (khl * 128 + wc * 64 + ml) * 8;
        short8v uH0 = *(const short8v*)(L + b0);
        short8v uL0 = *(const short8v*)(L + b0 + 2048);
        short8v vH0 = *(const short8v*)(L + b0 + 4096);
        short8v vL0 = *(const short8v*)(L + b0 + 6144);
        short8v uH1 = *(const short8v*)(L + b0 + 256);
        short8v uL1 = *(const short8v*)(L + b0 + 256 + 2048);
        short8v vH1 = *(const short8v*)(L + b0 + 256 + 4096);
        short8v vL1 = *(const short8v*)(L + b0 + 256 + 6144);
        accR0 = __builtin_amdgcn_mfma_f32_32x32x16_bf16(cH, uH0, accR0, 0, 0, 0);
        accR0 = __builtin_amdgcn_mfma_f32_32x32x16_bf16(cH, uL0, accR0, 0, 0, 0);
        accR0 = __builtin_amdgcn_mfma_f32_32x32x16_bf16(cL, uH0, accR0, 0, 0, 0);
        accI0 = __builtin_amdgcn_mfma_f32_32x32x16_bf16(sH, vH0, accI0, 0, 0, 0);
        accI0 = __builtin_amdgcn_mfma_f32_32x32x16_bf16(sH, vL0, accI0, 0, 0, 0);
        accI0 = __builtin_amdgcn_mfma_f32_32x32x16_bf16(sL, vH0, accI0, 0, 0, 0);
        accR1 = __builtin_amdgcn_mfma_f32_32x32x16_bf16(cH, uH1, accR1, 0, 0, 0);
        accR1 = __builtin_amdgcn_mfma_f32_32x32x16_bf16(cH, uL1, accR1, 0, 0, 0);
        accR1 = __builtin_amdgcn_mfma_f32_32x32x16_bf16(cL, uH1, accR1, 0, 0, 0);
        accI1 = __builtin_amdgcn_mfma_f32_32x32x16_bf16(sH, vH1, accI1, 0, 0, 0);
        accI1 = __builtin_amdgcn_mfma_f32_32x32x16_bf16(sH, vL1, accI1, 0, 0, 0);
        accI1 = __builtin_amdgcn_mfma_f32_32x32x16_bf16(sL, vH1, accI1, 0, 0, 0);
    };

    LOAD(0); WRITE(0); __syncthreads();
    for (int s = 0; s < 16; ++s) {
        if (s < 15) LOAD(s + 1);
        COMP(s & 1);
        if (s < 15) { WRITE((s + 1) & 1); __syncthreads(); }
    }

    if (part == 0) {   // odd-m correction: u[0] folded a1024 with +1 for all m
        const size_t b1024 = (size_t)b * 2048 * 512 + (size_t)1024 * 512 + chtile * 128;
        float a0 = src[b1024 + wc * 64 + ml];
        float a1 = src[b1024 + wc * 64 + 32 + ml];
#pragma unroll
        for (int reg = 1; reg < 16; reg += 2) { accR0[reg] -= 2.f * a0; accR1[reg] -= 2.f * a1; }
    }

    // epilogue: LDS transpose (stride 129) -> coalesced [p][h][m][e] stores
    float* LF = (float*)(&lds[0][0]);
#pragma unroll 1
    for (int pass = 0; pass < 2; ++pass) {
        __syncthreads();
#pragma unroll
        for (int reg = 0; reg < 16; ++reg) {
            const int m = wm * 32 + (reg & 3) + 8 * (reg >> 2) + 4 * khl;
            const int c0l = wc * 64 + ml;
            LF[m * 129 + c0l]      = pass ? accI0[reg] : accR0[reg];
            LF[m * 129 + c0l + 32] = pass ? accI1[reg] : accR1[reg];
        }
        __syncthreads();
#pragma unroll
        for (int u8 = 0; u8 < 8; ++u8) {
            int unit = tid + u8 * 256;              // 2048 units
            int e4 = unit & 3, h = (unit >> 2) & 7, m = unit >> 5;
            float4 val;
            val.x = LF[m * 129 + ((e4 * 4 + 0) * 8 + h)];
            val.y = LF[m * 129 + ((e4 * 4 + 1) * 8 + h)];
            val.z = LF[m * 129 + ((e4 * 4 + 2) * 8 + h)];
            val.w = LF[m * 129 + ((e4 * 4 + 3) * 8 + h)];
            *(float4*)&xp[pass * 32768 + (h * 64 + m) * 64 + chtile * 16 + e4 * 4] = val;
        }
    }
}

// Middle: per (b,h,x-half). 256 thr = 4 waves (wave -> 8 x-rows).
// S = Q K (complex), tanh, xqkv, scale -> YT (bf16 split, transposed)
__global__ __launch_bounds__(256) void mid_kernel(float* __restrict__ ws) {
    const int h = blockIdx.x, b = blockIdx.y, xh = blockIdx.z;
    unsigned short* __restrict__ YTb = (unsigned short*)ws + YT_U + (size_t)b * 131072;

    __shared__ float Qs[2][32][64];   // Q [xl][e]; reused as T [xl][y]
    __shared__ float Ksw[2][64][64];  // K [m][e] XOR-swizzled [m][e^m]

    const int tid = threadIdx.x;
    for (int slot = tid; slot < 1024; slot += 256) {   // p2 x 32m x 16f4
        int p = slot >> 9, ml = (slot >> 4) & 31, c4 = slot & 15;
        int off = ((p * 8 + h) * 64 + xh * 32 + ml) * 64 + c4 * 4;
        float4 acc = make_float4(0.f, 0.f, 0.f, 0.f);
#pragma unroll
        for (int part = 0; part < 4; ++part) {
            const float4 v = *(const float4*)(ws + XP_F + (size_t)(part * 16 + b) * 65536 + off);
            acc.x += v.x; acc.y += v.y; acc.z += v.z; acc.w += v.w;
        }
        *(float4*)(&Qs[p][ml][c4 * 4]) = acc;
    }
    for (int slot = tid; slot < 2048; slot += 256) {   // p2 x 64m x 16f4
        int p = slot >> 10, ml = (slot >> 4) & 63, c4 = slot & 15;
        int off = ((p * 8 + h) * 64 + ml) * 64 + c4 * 4;
        float4 acc = make_float4(0.f, 0.f, 0.f, 0.f);
#pragma unroll
        for (int part = 0; part < 4; ++part) {
            const float4 v = *(const float4*)(ws + XP_F + (size_t)((4 + part) * 16 + b) * 65536 + off);
            acc.x += v.x; acc.y += v.y; acc.z += v.z; acc.w += v.w;
        }
        Ksw[p][ml][(c4 * 4 + 0) ^ ml] = acc.x;
        Ksw[p][ml][(c4 * 4 + 1) ^ ml] = acc.y;
        Ksw[p][ml][(c4 * 4 + 2) ^ ml] = acc.z;
        Ksw[p][ml][(c4 * 4 + 3) ^ ml] = acc.w;
    }
    __syncthreads();

    const int lane = tid & 63;
    const int wid  = tid >> 6;   // 0..3
    const int xb   = wid * 8;

    float sr[8], si[8];
#pragma unroll
    for (int i = 0; i < 8; ++i) { sr[i] = 0.f; si[i] = 0.f; }
    const int y = lane;
    for (int e = 0; e < 64; ++e) {
        float kr = Ksw[0][y][e ^ y];
        float ki = Ksw[1][y][e ^ y];
#pragma unroll
        for (int i = 0; i < 8; ++i) {
            float qr = Qs[0][xb + i][e];
            float qi = Qs[1][xb + i][e];
            sr[i] += qr * kr; sr[i] -= qi * ki;
            si[i] += qr * ki; si[i] += qi * kr;
        }
    }
    float tr[8], ti[8];
#pragma unroll
    for (int i = 0; i < 8; ++i) { tr[i] = tanhf(sr[i]); ti[i] = tanhf(si[i]); }
    __syncthreads();
#pragma unroll
    for (int i = 0; i < 8; ++i) {
        Qs[0][xb + i][y] = tr[i];
        Qs[1][xb + i][y] = ti[i];
    }
    __syncthreads();

    float vr[8], vi[8];
#pragma unroll
    for (int i = 0; i < 8; ++i) { vr[i] = 0.f; vi[i] = 0.f; }
    const int e = lane;
    for (int yy = 0; yy < 64; ++yy) {
        float kr = Ksw[0][yy][e ^ yy];
        float ki = Ksw[1][yy][e ^ yy];
#pragma unroll
        for (int i = 0; i < 8; ++i) {
            float trr = Qs[0][xb + i][yy];
            float tii = Qs[1][xb + i][yy];
            vr[i] += trr * kr; vr[i] -= tii * ki;
            vi[i] += trr * ki; vi[i] += tii * kr;
        }
    }
#pragma unroll
    for (int i = 0; i < 8; ++i) {
        int x = xh * 32 + xb + i;
        float f = (x == 0 ? 1.0f : 2.0f) * (1.0f / (2048.0f * 4096.0f));
        float yr = f * vr[i];
        float yi = -f * vi[i];     // sign folded: out = P + Q with +sin table
        int off = (h * 64 + e) * 64 + x;
        unsigned short rH = bf16_rne(yr), iH = bf16_rne(yi);
        YTb[off]         = rH;
        YTb[32768 + off] = bf16_rne(yr - bf16_f(rH));
        YTb[65536 + off] = iH;
        YTb[98304 + off] = bf16_rne(yi - bf16_f(iH));
    }
}

// Inverse folded DFT via bf16-split MFMA. Block: 64t x 128ch; 4 waves (wt2 x wcc2),
// wave = 32t x 64ch (2 accs/side). Y staged in LDS from YT (m-slabs of 16, dbuf).
// P=sum cos*Yr, Q=sum sin*Yi; out[t]=P+Q (t<=1024), out[2048-t]=P-Q (1<=t<=1023).
__global__ __launch_bounds__(256, 3) void idft_kernel(const float* __restrict__ ws,
                                                      float* __restrict__ out) {
    const int tt0    = blockIdx.x * 64;   // 0..1024
    const int chtile = blockIdx.y;        // 0..3
    const int b      = blockIdx.z;
    const unsigned short* __restrict__ basisI = (const unsigned short*)ws + BI_U;
    const unsigned short* __restrict__ YTb = (const unsigned short*)ws + YT_U + (size_t)b * 131072;

    // [tbl4][ch128][24] per buffer = 12288 ushorts (stride 24 for alignment + banks)
    __shared__ __align__(16) unsigned short ldsY[2][12288];   // 48 KB

    const int tid  = threadIdx.x;
    const int lane = tid & 63;
    const int wv   = tid >> 6;
    const int wt   = wv >> 1, wcc = wv & 1;
    const int ml   = lane & 31;
    const int khl  = lane >> 5;

    f32x16 accP0, accP1, accQ0, accQ1;
#pragma unroll
    for (int i = 0; i < 16; ++i) { accP0[i] = 0.f; accP1[i] = 0.f; accQ0[i] = 0.f; accQ1[i] = 0.f; }

    const int tblA = tid >> 7;            // staging row A: tables 0,1
    const int chlA = tid & 127;
    short8v sA0, sA1, sB0, sB1;

    auto LOAD = [&](int s) {
        const unsigned short* gA = YTb + tblA * 32768 + (chtile * 128 + chlA) * 64 + s * 16;
        const unsigned short* gB = gA + 2 * 32768;      // tables 2,3
        sA0 = *(const short8v*)(gA);
        sA1 = *(const short8v*)(gA + 8);
        sB0 = *(const short8v*)(gB);
        sB1 = *(const short8v*)(gB + 8);
    };
    auto WRITE = [&](int bf) {
        unsigned short* D = &ldsY[bf][0];
        const int offA = tblA * 3072 + chlA * 24;
        *(short8v*)(D + offA)            = sA0;
        *(short8v*)(D + offA + 8)        = sA1;
        *(short8v*)(D + offA + 2 * 3072)     = sB0;
        *(short8v*)(D + offA + 2 * 3072 + 8) = sB1;
    };
    auto COMP = [&](int bf, int s) {
        const unsigned short* bb = basisI + (s * 8 + khl) * 8704 + (tt0 + wt * 32 + ml) * 8;
        short8v cH = *(const short8v*)(bb);
        short8v cL = *(const short8v*)(bb + 17408);
        short8v sH = *(const short8v*)(bb + 34816);
        short8v sL = *(const short8v*)(bb + 52224);
        const unsigned short* L = &ldsY[bf][0];
        const int b0 = (wcc * 64 + ml) * 24 + khl * 8;
        short8v yrH0 = *(const short8v*)(L + b0);
        short8v yrL0 = *(const short8v*)(L + 3072 + b0);
        short8v yiH0 = *(const short8v*)(L + 6144 + b0);
        short8v yiL0 = *(const short8v*)(L + 9216 + b0);
        const int b1 = b0 + 32 * 24;
        short8v yrH1 = *(const short8v*)(L + b1);
        short8v yrL1 = *(const short8v*)(L + 3072 + b1);
        short8v yiH1 = *(const short8v*)(L + 6144 + b1);
        short8v yiL1 = *(const short8v*)(L + 9216 + b1);
        accP0 = __builtin_amdgcn_mfma_f32_32x32x16_bf16(cH, yrH0, accP0, 0, 0, 0);
        accP0 = __builtin_amdgcn_mfma_f32_32x32x16_bf16(cH, yrL0, accP0, 0, 0, 0);
        accP0 = __builtin_amdgcn_mfma_f32_32x32x16_bf16(cL, yrH0, accP0, 0, 0, 0);
        accQ0 = __builtin_amdgcn_mfma_f32_32x32x16_bf16(sH, yiH0, accQ0, 0, 0, 0);
        accQ0 = __builtin_amdgcn_mfma_f32_32x32x16_bf16(sH, yiL0, accQ0, 0, 0, 0);
        accQ0 = __builtin_amdgcn_mfma_f32_32x32x16_bf16(sL, yiH0, accQ0, 0, 0, 0);
        accP1 = __builtin_amdgcn_mfma_f32_32x32x16_bf16(cH, yrH1, accP1, 0, 0, 0);
        accP1 = __builtin_amdgcn_mfma_f32_32x32x16_bf16(cH, yrL1, accP1, 0, 0, 0);
        accP1 = __builtin_amdgcn_mfma_f32_32x32x16_bf16(cL, yrH1, accP1, 0, 0, 0);
        accQ1 = __builtin_amdgcn_mfma_f32_32x32x16_bf16(sH, yiH1, accQ1, 0, 0, 0);
        accQ1 = __builtin_amdgcn_mfma_f32_32x32x16_bf16(sH, yiL1, accQ1, 0, 0, 0);
        accQ1 = __builtin_amdgcn_mfma_f32_32x32x16_bf16(sL, yiH1, accQ1, 0, 0, 0);
    };

    LOAD(0); WRITE(0); __syncthreads();
    for (int s = 0; s < 4; ++s) {
        if (s < 3) LOAD(s + 1);
        COMP(s & 1, s);
        if (s < 3) { WRITE((s + 1) & 1); __syncthreads(); }
    }

    float* __restrict__ ob = out + (size_t)b * 2048 * 512;
#pragma unroll
    for (int reg = 0; reg < 16; ++reg) {
        const int tL = wt * 32 + (reg & 3) + 8 * (reg >> 2) + 4 * khl;
        const int t  = tt0 + tL;
        const int ch0 = chtile * 128 + wcc * 64 + ml;
        float p0 = accP0[reg], q0 = accQ0[reg];
        float p1 = accP1[reg], q1 = accQ1[reg];
        if (t <= 1024) {
            ob[(size_t)t * 512 + ch0]      = p0 + q0;
            ob[(size_t)t * 512 + ch0 + 32] = p1 + q1;
        }
        if (t >= 1 && t <= 1023) {
            ob[(size_t)(2048 - t) * 512 + ch0]      = p0 - q0;
            ob[(size_t)(2048 - t) * 512 + ch0 + 32] = p1 - q1;
        }
    }
}

extern "C" void kernel_launch(void* const* d_in, const int* in_sizes, int n_in,
                              void* d_out, int out_size, void* d_ws, size_t ws_size,
                              hipStream_t stream) {
    const float* q = (const float*)d_in[0];
    const float* k = (const float*)d_in[1];
    float* ws = (float*)d_ws;      // ~38.8 MB used
    float* out = (float*)d_out;

    hipLaunchKernelGGL(basis_kernel, dim3(272), dim3(256), 0, stream, ws);
    hipLaunchKernelGGL(fdft_kernel, dim3(4, 16, 8), dim3(256), 0, stream, q, k, ws);
    hipLaunchKernelGGL(mid_kernel, dim3(8, 16, 2), dim3(256), 0, stream, ws);
    hipLaunchKernelGGL(idft_kernel, dim3(17, 4, 16), dim3(256), 0, stream, ws, out);
}